// Round 1
// 1283.251 us; speedup vs baseline: 1.3031x; 1.3031x over previous
//
#include <hip/hip_runtime.h>
#include <hip/hip_bf16.h>
#include <math.h>

// ---------------- problem constants ----------------
#define B_      2
#define L_      1024
#define HID     2048
#define T_      (B_*L_)      // 2048 tokens
#define NH      32
#define HD      64
#define NKV     8
#define INTER   8192
#define DSSM    2048
#define MH      32
#define MP      64
#define MS      64
#define MK      4
#define CONV_DIM 2176
#define QKV_N   3072
#define INPROJ_N 4256
#define CH      16     // scan chunks
#define CL      64     // chunk length

typedef __bf16 bf16x8 __attribute__((ext_vector_type(8)));
typedef __bf16 bf16x4 __attribute__((ext_vector_type(4)));
typedef float  floatx4 __attribute__((ext_vector_type(4)));

// ---------------- workspace layout (float elements) ----------------
// persistent
static const size_t OFF_H2   = 0;                       // 4,194,304 residual stream (fp32)
static const size_t OFF_MUP  = 4194304;                 // 16,384 slot
static const size_t AR       = 4210688;                 // arena base
// phase 1
static const size_t OFF_WQKV = AR;                      // bf16 6,291,456 el = 3,145,728 fl
static const size_t OFF_WIN  = OFF_WQKV + 3145728;      // bf16 8,716,288 el = 4,358,144 fl
static const size_t OFF_WO   = OFF_WIN  + 4358144;      // bf16 4,194,304 el = 2,097,152 fl
static const size_t OFF_WOP  = OFF_WO   + 2097152;      // bf16 4,194,304 el = 2,097,152 fl
static const size_t OFF_HSB  = OFF_WOP  + 2097152;      // bf16 hs_ln
static const size_t OFF_HSF  = OFF_HSB  + 2097152;      // fp32 hs_ln (dtfix)
static const size_t OFF_QKV  = OFF_HSF  + 4194304;      // fp32 6,291,456
static const size_t OFF_Q    = OFF_QKV  + 6291456;      // bf16 4,194,304 el
static const size_t OFF_K    = OFF_Q    + 2097152;      // bf16 1,048,576 el
static const size_t OFF_V    = OFF_K    + 524288;       // bf16 1,048,576 el
static const size_t OFF_ATT  = OFF_V    + 524288;       // bf16 4,194,304 el
static const size_t OFF_PROJ = OFF_ATT  + 2097152;      // fp32 8,716,288
static const size_t OFF_XBC  = OFF_PROJ + 8716288;      // fp32 4,456,448
static const size_t OFF_Y    = OFF_XBC  + 4456448;      // fp32 4,194,304
static const size_t OFF_G    = OFF_Y    + 4194304;      // bf16 4,194,304 el
// scan scratch aliases (qkv/q/v dead by scan time)
static const size_t OFF_TB   = OFF_QKV;                 // fp32 4,194,304 (Tbuf)
static const size_t OFF_DEC  = OFF_Q;                   // fp32 65,536
static const size_t OFF_LAM  = OFF_V;                   // fp32 1,024
// phase 2 (aliases phase-1 arena; everything above dead by MLP)
static const size_t OFF_HS2B = AR;                      // bf16 4,194,304 el
static const size_t OFF_GU   = AR + 2097152;            // fp32 33,554,432
static const size_t OFF_ACTB = OFF_GU + 33554432;       // bf16 16,777,216 el
static const size_t OFF_WB2  = OFF_ACTB + 8388608;      // bf16 16,777,216 el (gate/up/down_w time-shared)
// total = AR + 52,428,800 = 56,639,488 floats = 226.6 MB (< previous 234.9 MB proven)

// ---------------- helpers ----------------
__device__ inline float block_sum(float v, float* red) {
#pragma unroll
  for (int o = 32; o > 0; o >>= 1) v += __shfl_down(v, o, 64);
  const int lane = threadIdx.x & 63, wv = threadIdx.x >> 6;
  if (lane == 0) red[wv] = v;
  __syncthreads();
  if (threadIdx.x == 0) red[0] = red[0] + red[1] + red[2] + red[3];
  __syncthreads();
  float r = red[0];
  __syncthreads();
  return r;
}

__device__ inline bf16x8 pack8(float4 a, float4 b, float scale) {
  bf16x8 v;
  v[0] = (__bf16)(a.x * scale); v[1] = (__bf16)(a.y * scale);
  v[2] = (__bf16)(a.z * scale); v[3] = (__bf16)(a.w * scale);
  v[4] = (__bf16)(b.x * scale); v[5] = (__bf16)(b.y * scale);
  v[6] = (__bf16)(b.z * scale); v[7] = (__bf16)(b.w * scale);
  return v;
}

// async global->LDS 16B per lane (dest = wave-uniform base + lane*16)
__device__ __forceinline__ void async16(const void* g, void* l) {
  __builtin_amdgcn_global_load_lds(
      (const __attribute__((address_space(1))) void*)g,
      (__attribute__((address_space(3))) void*)l, 16, 0, 0);
}

// ---------------- fp32 -> bf16 conversion (grid-stride, x8) ----------------
__global__ __launch_bounds__(256) void cvt_kernel(
    const float* __restrict__ in, __bf16* __restrict__ outp, int n8)
{
  int i = blockIdx.x * 256 + threadIdx.x;
  const int stride = gridDim.x * 256;
  for (; i < n8; i += stride) {
    const float4* p = (const float4*)(in + (size_t)i * 8);
    float4 a = p[0], b = p[1];
    bf16x8 v;
    v[0] = (__bf16)a.x; v[1] = (__bf16)a.y; v[2] = (__bf16)a.z; v[3] = (__bf16)a.w;
    v[4] = (__bf16)b.x; v[5] = (__bf16)b.y; v[6] = (__bf16)b.z; v[7] = (__bf16)b.w;
    *(bf16x8*)(outp + (size_t)i * 8) = v;
  }
}

// ---------------- fp32 copy (outp <- h2 init for atomic down-GEMM) ----------
__global__ __launch_bounds__(256) void copy_kernel(
    const float* __restrict__ in, float* __restrict__ outp)
{
  const size_t i = ((size_t)blockIdx.x * 256 + threadIdx.x) * 4;
  *(float4*)&outp[i] = *(const float4*)&in[i];
}

// ---------------- GEMM (bf16 operands, global_load_lds staging) ------------
// out[m,n] (+)= alpha*colscale[n]*sum_k A[m,k]*W[n,k]; atomic accumulate when gridDim.z>1
__global__ __launch_bounds__(256) void gemm_bf_kernel(
    const __bf16* __restrict__ A, const __bf16* __restrict__ W,
    float* __restrict__ out, const float* __restrict__ addin,
    const float* __restrict__ colscale,
    int N, int K, int ldo, float alpha)
{
  __shared__ __align__(16) __bf16 As[128 * 32];   // [row][k] linear, 8 KB
  __shared__ __align__(16) __bf16 Bs[128 * 32];
  const int tid = threadIdx.x;
  const int lane = tid & 63, wave = tid >> 6;
  const int fr = lane & 15, fq = lane >> 4;
  const int m0 = blockIdx.x * 128, n0 = blockIdx.y * 128;
  const int wm = (wave >> 1) * 64, wn = (wave & 1) * 64;

  // split-K
  const int KS = K / gridDim.z;
  const int kbase = blockIdx.z * KS;

  // staging: wave w covers rows [w*32, w*32+32) via 2 calls of 16 rows each.
  // call c: LDS byte base (w*2+c)*1024; lane l -> row base+(l>>2), k-elems (l&3)*8
  const int srow = wave * 32 + (lane >> 2);
  const int selem = (lane & 3) * 8;
  const __bf16* ga0 = A + (size_t)(m0 + srow) * K + kbase + selem;
  const __bf16* ga1 = ga0 + (size_t)16 * K;
  int wr0 = n0 + srow;      if (wr0 >= N) wr0 = N - 1;   // clamp (N=4256 tail)
  int wr1 = n0 + srow + 16; if (wr1 >= N) wr1 = N - 1;
  const __bf16* gb0 = W + (size_t)wr0 * K + kbase + selem;
  const __bf16* gb1 = W + (size_t)wr1 * K + kbase + selem;
  __bf16* lA0 = &As[(wave * 2 + 0) * 512];
  __bf16* lA1 = &As[(wave * 2 + 1) * 512];
  __bf16* lB0 = &Bs[(wave * 2 + 0) * 512];
  __bf16* lB1 = &Bs[(wave * 2 + 1) * 512];

  floatx4 acc[4][4];
#pragma unroll
  for (int i = 0; i < 4; i++)
#pragma unroll
    for (int j = 0; j < 4; j++) acc[i][j] = (floatx4){0.f, 0.f, 0.f, 0.f};

  for (int kk = 0; kk < KS; kk += 32) {
    async16(ga0, lA0); async16(ga1, lA1);
    async16(gb0, lB0); async16(gb1, lB1);
    ga0 += 32; ga1 += 32; gb0 += 32; gb1 += 32;
    __syncthreads();   // compiler drains vmcnt before the barrier

    bf16x8 aF[4], bF[4];
#pragma unroll
    for (int i = 0; i < 4; i++)
      aF[i] = *(const bf16x8*)&As[(wm + i * 16 + fr) * 32 + fq * 8];
#pragma unroll
    for (int j = 0; j < 4; j++)
      bF[j] = *(const bf16x8*)&Bs[(wn + j * 16 + fr) * 32 + fq * 8];
#pragma unroll
    for (int i = 0; i < 4; i++)
#pragma unroll
      for (int j = 0; j < 4; j++)
        acc[i][j] = __builtin_amdgcn_mfma_f32_16x16x32_bf16(aF[i], bF[j], acc[i][j], 0, 0, 0);
    __syncthreads();
  }

  const bool at = (gridDim.z > 1);
#pragma unroll
  for (int i = 0; i < 4; i++) {
#pragma unroll
    for (int r = 0; r < 4; r++) {
      const int m = m0 + wm + i * 16 + fq * 4 + r;
      float* orow = out + (size_t)m * ldo;
      const float* arow = addin ? (addin + (size_t)m * ldo) : nullptr;
#pragma unroll
      for (int j = 0; j < 4; j++) {
        const int n = n0 + wn + j * 16 + fr;
        if (n < N) {
          float vv = acc[i][j][r] * alpha;
          if (colscale) vv *= colscale[n];
          if (at) {
            atomicAdd(&orow[n], vv);
          } else {
            if (arow) vv += arow[n];
            orow[n] = vv;
          }
        }
      }
    }
  }
}

// ---------------- RMSNorm (bf16 out + optional fp32 out + residual copy) ----
__global__ __launch_bounds__(256) void rms_kernel(
    const float* __restrict__ in, const float* __restrict__ w,
    __bf16* __restrict__ outb, float* __restrict__ outf, float* __restrict__ copy)
{
  __shared__ float buf[HID];
  __shared__ float red[8];
  const int tid = threadIdx.x;
  const size_t t = blockIdx.x;
  const float* row = in + t * HID;
  float ss = 0.f;
  for (int i = tid; i < HID; i += 256) { float x = row[i]; buf[i] = x; ss += x * x; }
  float tot = block_sum(ss, red);
  float inv = rsqrtf(tot / (float)HID + 1e-5f);
  for (int i = tid; i < HID; i += 256) {
    float x = buf[i];
    float val = x * inv * w[i];
    outb[t * HID + i] = (__bf16)val;
    if (outf) outf[t * HID + i] = val;
    if (copy) copy[t * HID + i] = x;
  }
}

// ---------------- mup column-scale vector ----------------
__global__ void mup_kernel(float* __restrict__ mup) {
  int i = blockIdx.x * 256 + threadIdx.x;
  if (i >= INPROJ_N) return;
  float v = (i < DSSM) ? 1.0f
          : (i < 2 * DSSM) ? 0.9f
          : (i < 2 * DSSM + MS) ? 0.8f
          : (i < 2 * DSSM + 2 * MS) ? 1.1f
          : 1.2f;
  mup[i] = v;
}

// ---------------- RoPE + split qkv (bf16 out; 0.125 softmax scale folded into q)
__global__ __launch_bounds__(256) void rope_kernel(
    const float* __restrict__ qkv, const int* __restrict__ positions,
    __bf16* __restrict__ q, __bf16* __restrict__ k, __bf16* __restrict__ v)
{
  __shared__ float inv_s[32];
  const int tid = threadIdx.x;
  const size_t t = blockIdx.x;
  const int l = (int)(t & (L_ - 1));
  if (tid < 32) inv_s[tid] = powf(1.0e11f, -(float)(2 * tid) / 64.f);
  __syncthreads();
  const float pos = (float)positions[l];
  const float* src = qkv + t * QKV_N;
  for (int idx = tid; idx < 1536; idx += 256) {
    int head = idx >> 5, hd = idx & 31;
    if (head < 32) {
      float ang = pos * inv_s[hd];
      float c = cosf(ang), sn = sinf(ang);
      float x1 = src[head * 64 + hd], x2 = src[head * 64 + 32 + hd];
      __bf16* dst = q + (t * NH + head) * HD;
      dst[hd] = (__bf16)((x1 * c - x2 * sn) * 0.125f);
      dst[hd + 32] = (__bf16)((x2 * c + x1 * sn) * 0.125f);
    } else if (head < 40) {
      int kk = head - 32;
      float ang = pos * inv_s[hd];
      float c = cosf(ang), sn = sinf(ang);
      float x1 = src[2048 + kk * 64 + hd] * 0.7f;
      float x2 = src[2048 + kk * 64 + 32 + hd] * 0.7f;
      __bf16* dst = k + (t * NKV + kk) * HD;
      dst[hd] = (__bf16)(x1 * c - x2 * sn);
      dst[hd + 32] = (__bf16)(x2 * c + x1 * sn);
    } else {
      int vv = head - 40;
      __bf16* dst = v + (t * NKV + vv) * HD;
      dst[hd] = (__bf16)src[2560 + vv * 64 + hd];
      dst[hd + 32] = (__bf16)src[2560 + vv * 64 + 32 + hd];
    }
  }
}

// ---------------- flash attention, bf16 in/out, 64-query tile per block -----
__global__ __launch_bounds__(256) void fattn_kernel(
    const __bf16* __restrict__ q, const __bf16* __restrict__ k,
    const __bf16* __restrict__ v, __bf16* __restrict__ out)
{
  __shared__ __align__(16) __bf16 Vt[64][72];      // [dim][key]
  __shared__ __align__(16) __bf16 Ps[4][16][72];   // per-wave P strip [q16][key]
  const int tid = threadIdx.x;
  const int wave = tid >> 6, lane = tid & 63;
  const int fr = lane & 15, fq = lane >> 4;
  const int qt = (int)(gridDim.x - 1) - blockIdx.x;   // big tiles dispatch first
  const int h = blockIdx.y, b = blockIdx.z, g = h >> 2;
  const int l0 = qt * 64;

  bf16x8 qf[2];
  {
    const int qrow = l0 + wave * 16 + fr;
    const __bf16* qp = q + (((size_t)(b * L_ + qrow)) * NH + h) * HD;
    qf[0] = *(const bf16x8*)&qp[fq * 8];
    qf[1] = *(const bf16x8*)&qp[32 + fq * 8];
  }

  floatx4 O[4];
  float m_run[4], l_run[4];
#pragma unroll
  for (int i = 0; i < 4; i++) { O[i] = (floatx4){0.f,0.f,0.f,0.f}; m_run[i] = -3.0e38f; l_run[i] = 0.f; }

  for (int kt = 0; kt <= qt; kt++) {
    __syncthreads();
#pragma unroll
    for (int pp = 0; pp < 4; pp++) {
      const int kb = pp * 4 + wave;
      bf16x4 pk;
#pragma unroll
      for (int c = 0; c < 4; c++)
        pk[c] = v[(((size_t)(b * L_ + kt * 64 + kb * 4 + c)) * NKV + g) * HD + lane];
      *(bf16x4*)&Vt[lane][kb * 4] = pk;
    }

    floatx4 S[4];
#pragma unroll
    for (int j = 0; j < 4; j++) {
      const __bf16* kp = k + (((size_t)(b * L_ + kt * 64 + j * 16 + fr)) * NKV + g) * HD;
      floatx4 sa = (floatx4){0.f,0.f,0.f,0.f};
#pragma unroll
      for (int s = 0; s < 2; s++) {
        bf16x8 kf = *(const bf16x8*)&kp[s * 32 + fq * 8];
        sa = __builtin_amdgcn_mfma_f32_16x16x32_bf16(qf[s], kf, sa, 0, 0, 0);
      }
      S[j] = sa;
    }

    if (kt == qt) {
      const int qbase = wave * 16 + fq * 4;
#pragma unroll
      for (int j = 0; j < 4; j++)
#pragma unroll
        for (int r = 0; r < 4; r++)
          if (j * 16 + fr > qbase + r) S[j][r] = -1.0e30f;
    }

    float rm[4], alpha[4], rsum[4];
#pragma unroll
    for (int r = 0; r < 4; r++)
      rm[r] = fmaxf(fmaxf(S[0][r], S[1][r]), fmaxf(S[2][r], S[3][r]));
#pragma unroll
    for (int msk = 1; msk <= 8; msk <<= 1)
#pragma unroll
      for (int r = 0; r < 4; r++) rm[r] = fmaxf(rm[r], __shfl_xor(rm[r], msk, 64));
#pragma unroll
    for (int r = 0; r < 4; r++) {
      float mnew = fmaxf(m_run[r], rm[r]);
      alpha[r] = __expf(m_run[r] - mnew);
      m_run[r] = mnew;
    }
#pragma unroll
    for (int j = 0; j < 4; j++)
#pragma unroll
      for (int r = 0; r < 4; r++) S[j][r] = __expf(S[j][r] - m_run[r]);
#pragma unroll
    for (int r = 0; r < 4; r++)
      rsum[r] = S[0][r] + S[1][r] + S[2][r] + S[3][r];
#pragma unroll
    for (int msk = 1; msk <= 8; msk <<= 1)
#pragma unroll
      for (int r = 0; r < 4; r++) rsum[r] += __shfl_xor(rsum[r], msk, 64);
#pragma unroll
    for (int r = 0; r < 4; r++) l_run[r] = l_run[r] * alpha[r] + rsum[r];
#pragma unroll
    for (int d4 = 0; d4 < 4; d4++)
#pragma unroll
      for (int r = 0; r < 4; r++) O[d4][r] *= alpha[r];

#pragma unroll
    for (int j = 0; j < 4; j++)
#pragma unroll
      for (int r = 0; r < 4; r++)
        Ps[wave][fq * 4 + r][j * 16 + fr] = (__bf16)S[j][r];

    __syncthreads();

#pragma unroll
    for (int s = 0; s < 2; s++) {
      bf16x8 pf = *(const bf16x8*)&Ps[wave][fr][s * 32 + fq * 8];
#pragma unroll
      for (int d4 = 0; d4 < 4; d4++) {
        bf16x8 vf = *(const bf16x8*)&Vt[d4 * 16 + fr][s * 32 + fq * 8];
        O[d4] = __builtin_amdgcn_mfma_f32_16x16x32_bf16(pf, vf, O[d4], 0, 0, 0);
      }
    }
  }

  float rl[4];
#pragma unroll
  for (int r = 0; r < 4; r++) rl[r] = 1.f / l_run[r];
#pragma unroll
  for (int d4 = 0; d4 < 4; d4++)
#pragma unroll
    for (int r = 0; r < 4; r++) {
      const int qg = l0 + wave * 16 + fq * 4 + r;
      out[((size_t)(b * L_ + qg)) * HID + h * 64 + d4 * 16 + fr] = (__bf16)(O[d4][r] * rl[r]);
    }
}

// ---------------- exact-fp32 recompute of the 32 dt columns of in_proj ------
__global__ __launch_bounds__(256) void dtfix_kernel(
    const float* __restrict__ hs_ln, const float* __restrict__ w, float* __restrict__ proj)
{
  const size_t t = blockIdx.x;
  const int tid = threadIdx.x;
  const int o = tid >> 3, part = tid & 7;
  const float* a = hs_ln + t * HID;
  const float* wr = w + (size_t)(INPROJ_N - MH + o) * HID;
  float s = 0.f;
  for (int kk = part * 4; kk < HID; kk += 32) {
    const float4 av = *(const float4*)&a[kk];
    const float4 wv = *(const float4*)&wr[kk];
    s += av.x * wv.x + av.y * wv.y + av.z * wv.z + av.w * wv.w;
  }
  s += __shfl_xor(s, 1);
  s += __shfl_xor(s, 2);
  s += __shfl_xor(s, 4);
  if (part == 0) proj[t * INPROJ_N + (INPROJ_N - MH) + o] = s * 1.32f; // SSM_IN*mup_dt
}

// ---------------- depthwise causal conv (MK=4) + bias + silu ----------------
__global__ __launch_bounds__(256) void conv_kernel(
    const float* __restrict__ proj, const float* __restrict__ cw,
    const float* __restrict__ cb, float* __restrict__ xbc)
{
  const int c = blockIdx.x * 256 + threadIdx.x;
  if (c >= CONV_DIM) return;
  const int t = blockIdx.y;
  const int l = t & (L_ - 1);
  float acc = cb[c];
#pragma unroll
  for (int kk = 0; kk < MK; kk++) {
    int lp = l - (MK - 1) + kk;
    if (lp >= 0)
      acc += proj[((size_t)(t - (MK - 1) + kk)) * INPROJ_N + DSSM + c] * cw[c * MK + kk];
  }
  xbc[(size_t)t * CONV_DIM + c] = acc / (1.f + __expf(-acc));
}

// ---------------- chunked Mamba2 scan, stage A: intra-chunk (MFMA) ----------
__global__ __launch_bounds__(256) void scanA_kernel(
    const float* __restrict__ xbc, const float* __restrict__ proj,
    const float* __restrict__ A_log, const float* __restrict__ dt_bias,
    const float* __restrict__ Dp,
    float* __restrict__ y, float* __restrict__ Tbuf,
    float* __restrict__ lam, float* __restrict__ dec)
{
  __shared__ __align__(16) __bf16 xT[64][72];    // [p][l]
  __shared__ __align__(16) __bf16 BTw[64][72];   // [s][l] (scaled)
  __shared__ __align__(16) __bf16 Braw[64][72];  // [l][s]
  __shared__ __align__(16) __bf16 Craw[64][72];  // [l][s]
  __shared__ __align__(16) __bf16 Ps[4][16][72]; // per-wave M strip
  __shared__ float dt_s[64], cum_s[64];

  const int tid = threadIdx.x;
  const int lane = tid & 63, wave = tid >> 6;
  const int fr = lane & 15, fq = lane >> 4;
  const int c = blockIdx.x, h = blockIdx.y, b = blockIdx.z;
  const int t0 = b * L_ + c * CL;
  const float Ah = -expf(A_log[h]);
  const float dtb = dt_bias[h], Dh = Dp[h];

  if (wave == 0) {
    float draw = proj[(size_t)(t0 + lane) * INPROJ_N + (INPROJ_N - MH) + h];
    float dtv = draw + dtb;
    dtv = (dtv > 20.f) ? dtv : log1pf(__expf(dtv));
    float cs = dtv * Ah;
#pragma unroll
    for (int d = 1; d < 64; d <<= 1) {
      float nv = __shfl_up(cs, d, 64);
      if (lane >= d) cs += nv;
    }
    dt_s[lane] = dtv;
    cum_s[lane] = cs;
  }

#pragma unroll
  for (int pass = 0; pass < 4; pass++) {
    const int l = pass * 16 + (tid >> 4);
    const int s4 = (tid & 15) * 4;
    const float* rowp = xbc + (size_t)(t0 + l) * CONV_DIM;
    float4 xv = *(const float4*)&rowp[h * 64 + s4];
    float4 bv = *(const float4*)&rowp[DSSM + s4];
    float4 cv = *(const float4*)&rowp[DSSM + MS + s4];
    xT[s4 + 0][l] = (__bf16)xv.x;
    xT[s4 + 1][l] = (__bf16)xv.y;
    xT[s4 + 2][l] = (__bf16)xv.z;
    xT[s4 + 3][l] = (__bf16)xv.w;
    bf16x4 b4; b4[0]=(__bf16)bv.x; b4[1]=(__bf16)bv.y; b4[2]=(__bf16)bv.z; b4[3]=(__bf16)bv.w;
    *(bf16x4*)&Braw[l][s4] = b4;
    bf16x4 c4; c4[0]=(__bf16)cv.x; c4[1]=(__bf16)cv.y; c4[2]=(__bf16)cv.z; c4[3]=(__bf16)cv.w;
    *(bf16x4*)&Craw[l][s4] = c4;
  }
  __syncthreads();

  const float cend = cum_s[63];
#pragma unroll
  for (int pass = 0; pass < 4; pass++) {
    const int l = pass * 16 + (tid >> 4);
    const int s4 = (tid & 15) * 4;
    const float wl = __expf(cend - cum_s[l]) * dt_s[l];
    float4 bv = *(const float4*)&xbc[(size_t)(t0 + l) * CONV_DIM + DSSM + s4];
    BTw[s4 + 0][l] = (__bf16)(bv.x * wl);
    BTw[s4 + 1][l] = (__bf16)(bv.y * wl);
    BTw[s4 + 2][l] = (__bf16)(bv.z * wl);
    BTw[s4 + 3][l] = (__bf16)(bv.w * wl);
  }

  {
    bf16x8 aF0 = *(const bf16x8*)&Craw[wave * 16 + fr][fq * 8];
    bf16x8 aF1 = *(const bf16x8*)&Craw[wave * 16 + fr][fq * 8 + 32];
#pragma unroll
    for (int j = 0; j < 4; j++) {
      floatx4 s = (floatx4){0.f,0.f,0.f,0.f};
      bf16x8 b0 = *(const bf16x8*)&Braw[j * 16 + fr][fq * 8];
      bf16x8 b1 = *(const bf16x8*)&Braw[j * 16 + fr][fq * 8 + 32];
      s = __builtin_amdgcn_mfma_f32_16x16x32_bf16(aF0, b0, s, 0, 0, 0);
      s = __builtin_amdgcn_mfma_f32_16x16x32_bf16(aF1, b1, s, 0, 0, 0);
      const int m = j * 16 + fr;
      const float dtm = dt_s[m], cmm = cum_s[m];
#pragma unroll
      for (int r = 0; r < 4; r++) {
        const int lR = wave * 16 + fq * 4 + r;
        float f = (m <= lR) ? __expf(cum_s[lR] - cmm) * dtm : 0.f;
        Ps[wave][fq * 4 + r][m] = (__bf16)(s[r] * f);
      }
    }
  }
  __syncthreads();

  {
    bf16x8 aF0 = *(const bf16x8*)&Ps[wave][fr][fq * 8];
    bf16x8 aF1 = *(const bf16x8*)&Ps[wave][fr][fq * 8 + 32];
#pragma unroll
    for (int j = 0; j < 4; j++) {
      floatx4 s = (floatx4){0.f,0.f,0.f,0.f};
      bf16x8 b0 = *(const bf16x8*)&xT[j * 16 + fr][fq * 8];
      bf16x8 b1 = *(const bf16x8*)&xT[j * 16 + fr][fq * 8 + 32];
      s = __builtin_amdgcn_mfma_f32_16x16x32_bf16(aF0, b0, s, 0, 0, 0);
      s = __builtin_amdgcn_mfma_f32_16x16x32_bf16(aF1, b1, s, 0, 0, 0);
      const int p = j * 16 + fr;
#pragma unroll
      for (int r = 0; r < 4; r++) {
        const int lR = wave * 16 + fq * 4 + r;
        float xval = (float)xT[p][lR];
        y[(size_t)(t0 + lR) * DSSM + h * 64 + p] = s[r] + Dh * xval;
      }
    }
  }

  {
    float* Tb = Tbuf + ((size_t)((b * MH + h) * CH + c)) * 4096;
    bf16x8 aF0 = *(const bf16x8*)&xT[wave * 16 + fr][fq * 8];
    bf16x8 aF1 = *(const bf16x8*)&xT[wave * 16 + fr][fq * 8 + 32];
#pragma unroll
    for (int j = 0; j < 4; j++) {
      floatx4 s = (floatx4){0.f,0.f,0.f,0.f};
      bf16x8 b0 = *(const bf16x8*)&BTw[j * 16 + fr][fq * 8];
      bf16x8 b1 = *(const bf16x8*)&BTw[j * 16 + fr][fq * 8 + 32];
      s = __builtin_amdgcn_mfma_f32_16x16x32_bf16(aF0, b0, s, 0, 0, 0);
      s = __builtin_amdgcn_mfma_f32_16x16x32_bf16(aF1, b1, s, 0, 0, 0);
#pragma unroll
      for (int r = 0; r < 4; r++)
        Tb[(wave * 16 + fq * 4 + r) * 64 + j * 16 + fr] = s[r];
    }
  }

  if (tid == 0) lam[(b * MH + h) * CH + c] = __expf(cend);
  if (tid >= 64 && tid < 128)
    dec[((size_t)((b * MH + h) * CH + c)) * 64 + (tid - 64)] = __expf(cum_s[tid - 64]);
}

// ---------------- chunked scan, stage B: inter-chunk state scan -------------
__global__ __launch_bounds__(256) void scanB_kernel(
    const float* __restrict__ xbc, const float* __restrict__ Tbuf,
    const float* __restrict__ lam, const float* __restrict__ dec,
    float* __restrict__ y)
{
  __shared__ __align__(16) float S[64][68];
  __shared__ __align__(16) __bf16 Cc[64][72];
  __shared__ float decl[64];
  const int tid = threadIdx.x;
  const int lane = tid & 63, wave = tid >> 6;
  const int fr = lane & 15, fq = lane >> 4;
  const int h = blockIdx.x, b = blockIdx.y;

  const int sown = tid & 63, pbase = (tid >> 6) * 16;
#pragma unroll
  for (int i = 0; i < 16; i++) S[pbase + i][sown] = 0.f;
  __syncthreads();

  for (int c = 0; c < CH; c++) {
    const int t0 = b * L_ + c * CL;
#pragma unroll
    for (int pass = 0; pass < 4; pass++) {
      const int l = pass * 16 + (tid >> 4);
      const int s4 = (tid & 15) * 4;
      float4 cv = *(const float4*)&xbc[(size_t)(t0 + l) * CONV_DIM + DSSM + MS + s4];
      bf16x4 c4; c4[0]=(__bf16)cv.x; c4[1]=(__bf16)cv.y; c4[2]=(__bf16)cv.z; c4[3]=(__bf16)cv.w;
      *(bf16x4*)&Cc[l][s4] = c4;
    }
    if (tid < 64) decl[tid] = dec[((size_t)((b * MH + h) * CH + c)) * 64 + tid];
    __syncthreads();

    if (c > 0) {
      bf16x8 aF0 = *(const bf16x8*)&Cc[wave * 16 + fr][fq * 8];
      bf16x8 aF1 = *(const bf16x8*)&Cc[wave * 16 + fr][fq * 8 + 32];
#pragma unroll
      for (int j = 0; j < 4; j++) {
        const float* srow = &S[j * 16 + fr][0];
        float4 s0 = *(const float4*)&srow[fq * 8];
        float4 s1 = *(const float4*)&srow[fq * 8 + 4];
        float4 s2 = *(const float4*)&srow[fq * 8 + 32];
        float4 s3 = *(const float4*)&srow[fq * 8 + 36];
        bf16x8 b0 = pack8(s0, s1, 1.f);
        bf16x8 b1 = pack8(s2, s3, 1.f);
        floatx4 acc = (floatx4){0.f,0.f,0.f,0.f};
        acc = __builtin_amdgcn_mfma_f32_16x16x32_bf16(aF0, b0, acc, 0, 0, 0);
        acc = __builtin_amdgcn_mfma_f32_16x16x32_bf16(aF1, b1, acc, 0, 0, 0);
        const int p = j * 16 + fr;
#pragma unroll
        for (int r = 0; r < 4; r++) {
          const int lR = wave * 16 + fq * 4 + r;
          float* yp = &y[(size_t)(t0 + lR) * DSSM + h * 64 + p];
          *yp += decl[lR] * acc[r];
        }
      }
    }
    __syncthreads();

    const float lc = lam[(b * MH + h) * CH + c];
    const float* Tb = Tbuf + ((size_t)((b * MH + h) * CH + c)) * 4096;
#pragma unroll
    for (int i = 0; i < 16; i++) {
      float tv = Tb[(pbase + i) * 64 + sown];
      S[pbase + i][sown] = lc * S[pbase + i][sown] + tv;
    }
    __syncthreads();
  }
}

// ---------------- gating (y * silu(z)) + RMSNorm -> bf16 ----------------
__global__ __launch_bounds__(256) void gating_kernel(
    const float* __restrict__ y, const float* __restrict__ proj,
    const float* __restrict__ nw, __bf16* __restrict__ g)
{
  __shared__ float buf[DSSM];
  __shared__ float red[8];
  const int tid = threadIdx.x;
  const size_t t = blockIdx.x;
  float ss = 0.f;
  for (int i = tid; i < DSSM; i += 256) {
    float zv = proj[t * INPROJ_N + i];
    float yv = y[t * DSSM + i];
    float gv = yv * zv / (1.f + __expf(-zv));
    buf[i] = gv;
    ss += gv * gv;
  }
  float tot = block_sum(ss, red);
  float inv = rsqrtf(tot / (float)DSSM + 1e-5f);
  for (int i = tid; i < DSSM; i += 256) g[t * DSSM + i] = (__bf16)(buf[i] * inv * nw[i]);
}

// ---------------- SwiGLU activation -> bf16 (x4 vectorized) ----------------
__global__ __launch_bounds__(256) void act_kernel(
    const float* __restrict__ gu, __bf16* __restrict__ act)
{
  const int i = (blockIdx.x * 256 + threadIdx.x) * 4;
  const size_t t = blockIdx.y;
  float4 g4 = *(const float4*)&gu[t * (2 * INTER) + i];
  float4 u4 = *(const float4*)&gu[t * (2 * INTER) + INTER + i];
  bf16x4 o;
  float gt;
  gt = g4.x * 0.9f; o[0] = (__bf16)(gt / (1.f + __expf(-gt)) * u4.x);
  gt = g4.y * 0.9f; o[1] = (__bf16)(gt / (1.f + __expf(-gt)) * u4.y);
  gt = g4.z * 0.9f; o[2] = (__bf16)(gt / (1.f + __expf(-gt)) * u4.z);
  gt = g4.w * 0.9f; o[3] = (__bf16)(gt / (1.f + __expf(-gt)) * u4.w);
  *(bf16x4*)&act[t * INTER + i] = o;
}

// ---------------- launcher ----------------
extern "C" void kernel_launch(void* const* d_in, const int* in_sizes, int n_in,
                              void* d_out, int out_size, void* d_ws, size_t ws_size,
                              hipStream_t stream)
{
  const float* hidden      = (const float*)d_in[0];
  const int*   positions   = (const int*)d_in[1];
  const float* w_in_ln     = (const float*)d_in[2];
  const float* qkv_w       = (const float*)d_in[3];
  const float* o_w         = (const float*)d_in[4];
  const float* in_proj_w   = (const float*)d_in[5];
  const float* conv_w      = (const float*)d_in[6];
  const float* conv_b      = (const float*)d_in[7];
  const float* A_log       = (const float*)d_in[8];
  const float* dt_bias     = (const float*)d_in[9];
  const float* Dp          = (const float*)d_in[10];
  const float* ssm_norm_w  = (const float*)d_in[11];
  const float* out_proj_w  = (const float*)d_in[12];
  const float* w_pre_ff_ln = (const float*)d_in[13];
  const float* gate_up_w   = (const float*)d_in[14];
  const float* down_w      = (const float*)d_in[15];
  (void)in_sizes; (void)n_in; (void)out_size; (void)ws_size;

  float* ws   = (float*)d_ws;
  float* outp = (float*)d_out;

  float*  h2    = ws + OFF_H2;
  float*  mup   = ws + OFF_MUP;
  __bf16* wqkv  = (__bf16*)(ws + OFF_WQKV);
  __bf16* win   = (__bf16*)(ws + OFF_WIN);
  __bf16* wo    = (__bf16*)(ws + OFF_WO);
  __bf16* wop   = (__bf16*)(ws + OFF_WOP);
  __bf16* hsb   = (__bf16*)(ws + OFF_HSB);
  float*  hsf   = ws + OFF_HSF;
  float*  qkv   = ws + OFF_QKV;
  __bf16* qb    = (__bf16*)(ws + OFF_Q);
  __bf16* kb    = (__bf16*)(ws + OFF_K);
  __bf16* vb    = (__bf16*)(ws + OFF_V);
  __bf16* attb  = (__bf16*)(ws + OFF_ATT);
  float*  proj  = ws + OFF_PROJ;
  float*  xbc   = ws + OFF_XBC;
  float*  y     = ws + OFF_Y;
  __bf16* gb    = (__bf16*)(ws + OFF_G);
  float*  Tbuf  = ws + OFF_TB;
  float*  dec   = ws + OFF_DEC;
  float*  lam   = ws + OFF_LAM;
  __bf16* hs2b  = (__bf16*)(ws + OFF_HS2B);
  float*  gu    = ws + OFF_GU;
  __bf16* actb  = (__bf16*)(ws + OFF_ACTB);
  __bf16* wb2   = (__bf16*)(ws + OFF_WB2);

  // phase-1 weight conversions (fp32 -> bf16)
  cvt_kernel<<<2048, 256, 0, stream>>>(qkv_w, wqkv, 786432);
  cvt_kernel<<<2048, 256, 0, stream>>>(in_proj_w, win, 1089536);
  cvt_kernel<<<2048, 256, 0, stream>>>(o_w, wo, 524288);
  cvt_kernel<<<2048, 256, 0, stream>>>(out_proj_w, wop, 524288);
  mup_kernel<<<17, 256, 0, stream>>>(mup);
  rms_kernel<<<T_, 256, 0, stream>>>(hidden, w_in_ln, hsb, hsf, h2);

  // attention branch
  gemm_bf_kernel<<<dim3(16, 24, 1), 256, 0, stream>>>(hsb, wqkv, qkv, nullptr, nullptr,
                                                      QKV_N, HID, QKV_N, 1.2f);
  rope_kernel<<<T_, 256, 0, stream>>>(qkv, positions, qb, kb, vb);
  fattn_kernel<<<dim3(L_ / 64, NH, B_), 256, 0, stream>>>(qb, kb, vb, attb);
  gemm_bf_kernel<<<dim3(16, 16, 4), 256, 0, stream>>>(attb, wo, h2, nullptr, nullptr,
                                                      HID, HID, HID, 0.8f);   // atomic += into residual

  // mamba branch
  gemm_bf_kernel<<<dim3(16, 34, 1), 256, 0, stream>>>(hsb, win, proj, nullptr, mup,
                                                      INPROJ_N, HID, INPROJ_N, 1.1f);
  dtfix_kernel<<<T_, 256, 0, stream>>>(hsf, in_proj_w, proj);
  conv_kernel<<<dim3(9, T_), 256, 0, stream>>>(proj, conv_w, conv_b, xbc);
  scanA_kernel<<<dim3(CH, MH, B_), 256, 0, stream>>>(xbc, proj, A_log, dt_bias, Dp,
                                                     y, Tbuf, lam, dec);
  scanB_kernel<<<dim3(MH, B_), 256, 0, stream>>>(xbc, Tbuf, lam, dec, y);
  gating_kernel<<<T_, 256, 0, stream>>>(y, proj, ssm_norm_w, gb);
  gemm_bf_kernel<<<dim3(16, 16, 4), 256, 0, stream>>>(gb, wop, h2, nullptr, nullptr,
                                                      HID, HID, HID, 0.9f);   // atomic += into residual

  // MLP (wb2 time-shared: gate half -> up half -> down_w)
  rms_kernel<<<T_, 256, 0, stream>>>(h2, w_pre_ff_ln, hs2b, nullptr, nullptr);
  cvt_kernel<<<2048, 256, 0, stream>>>(gate_up_w, wb2, 2097152);
  gemm_bf_kernel<<<dim3(16, 64, 1), 256, 0, stream>>>(hs2b, wb2, gu, nullptr, nullptr,
                                                      INTER, HID, 2 * INTER, 1.0f);
  cvt_kernel<<<2048, 256, 0, stream>>>(gate_up_w + (size_t)INTER * HID, wb2, 2097152);
  gemm_bf_kernel<<<dim3(16, 64, 1), 256, 0, stream>>>(hs2b, wb2, gu + INTER, nullptr, nullptr,
                                                      INTER, HID, 2 * INTER, 1.0f);
  act_kernel<<<dim3(INTER / 1024, T_), 256, 0, stream>>>(gu, actb);
  cvt_kernel<<<2048, 256, 0, stream>>>(down_w, wb2, 2097152);
  copy_kernel<<<4096, 256, 0, stream>>>(h2, outp);
  gemm_bf_kernel<<<dim3(16, 16, 4), 256, 0, stream>>>(actb, wb2, outp, nullptr, nullptr,
                                                      HID, INTER, HID, 0.8f); // atomic += onto residual copy
}

// Round 2
// 1265.055 us; speedup vs baseline: 1.3219x; 1.0144x over previous
//
#include <hip/hip_runtime.h>
#include <hip/hip_bf16.h>
#include <math.h>

// ---------------- problem constants ----------------
#define B_      2
#define L_      1024
#define HID     2048
#define T_      (B_*L_)      // 2048 tokens
#define NH      32
#define HD      64
#define NKV     8
#define INTER   8192
#define DSSM    2048
#define MH      32
#define MP      64
#define MS      64
#define MK      4
#define CONV_DIM 2176
#define QKV_N   3072
#define INPROJ_N 4256
#define CH      16     // scan chunks
#define CL      64     // chunk length

typedef __bf16 bf16x8 __attribute__((ext_vector_type(8)));
typedef __bf16 bf16x4 __attribute__((ext_vector_type(4)));
typedef float  floatx4 __attribute__((ext_vector_type(4)));

// ---------------- workspace layout (float elements) ----------------
// persistent
static const size_t OFF_H2   = 0;                       // 4,194,304 residual stream (fp32)
static const size_t OFF_MUP  = 4194304;                 // 16,384 slot
static const size_t AR       = 4210688;                 // arena base
// phase 1
static const size_t OFF_WQKV = AR;                      // bf16 6,291,456 el = 3,145,728 fl
static const size_t OFF_WIN  = OFF_WQKV + 3145728;      // bf16 8,716,288 el = 4,358,144 fl
static const size_t OFF_WO   = OFF_WIN  + 4358144;      // bf16 4,194,304 el = 2,097,152 fl
static const size_t OFF_WOP  = OFF_WO   + 2097152;      // bf16 4,194,304 el = 2,097,152 fl
static const size_t OFF_HSB  = OFF_WOP  + 2097152;      // bf16 hs_ln
static const size_t OFF_HSF  = OFF_HSB  + 2097152;      // fp32 hs_ln (dtfix)
static const size_t OFF_QKV  = OFF_HSF  + 4194304;      // fp32 6,291,456
static const size_t OFF_Q    = OFF_QKV  + 6291456;      // bf16 4,194,304 el
static const size_t OFF_K    = OFF_Q    + 2097152;      // bf16 1,048,576 el
static const size_t OFF_V    = OFF_K    + 524288;       // bf16 1,048,576 el
static const size_t OFF_ATT  = OFF_V    + 524288;       // bf16 4,194,304 el
static const size_t OFF_PROJ = OFF_ATT  + 2097152;      // fp32 8,716,288
static const size_t OFF_XBC  = OFF_PROJ + 8716288;      // fp32 4,456,448
static const size_t OFF_Y    = OFF_XBC  + 4456448;      // fp32 4,194,304
static const size_t OFF_G    = OFF_Y    + 4194304;      // bf16 4,194,304 el
// scan scratch aliases (qkv/q/v dead by scan time)
static const size_t OFF_TB   = OFF_QKV;                 // fp32 4,194,304 (Tbuf)
static const size_t OFF_DEC  = OFF_Q;                   // fp32 65,536
static const size_t OFF_LAM  = OFF_V;                   // fp32 1,024
// phase 2 (aliases phase-1 arena; everything above dead by MLP)
static const size_t OFF_HS2B = AR;                      // bf16 4,194,304 el
static const size_t OFF_GU   = AR + 2097152;            // fp32 33,554,432
static const size_t OFF_ACTB = OFF_GU + 33554432;       // bf16 16,777,216 el
static const size_t OFF_WB2  = OFF_ACTB + 8388608;      // bf16 16,777,216 el (gate/up/down_w time-shared)
// total = AR + 52,428,800 = 56,639,488 floats = 226.6 MB

// ---------------- helpers ----------------
__device__ inline float block_sum(float v, float* red) {
#pragma unroll
  for (int o = 32; o > 0; o >>= 1) v += __shfl_down(v, o, 64);
  const int lane = threadIdx.x & 63, wv = threadIdx.x >> 6;
  if (lane == 0) red[wv] = v;
  __syncthreads();
  if (threadIdx.x == 0) red[0] = red[0] + red[1] + red[2] + red[3];
  __syncthreads();
  float r = red[0];
  __syncthreads();
  return r;
}

__device__ inline bf16x8 pack8(float4 a, float4 b, float scale) {
  bf16x8 v;
  v[0] = (__bf16)(a.x * scale); v[1] = (__bf16)(a.y * scale);
  v[2] = (__bf16)(a.z * scale); v[3] = (__bf16)(a.w * scale);
  v[4] = (__bf16)(b.x * scale); v[5] = (__bf16)(b.y * scale);
  v[6] = (__bf16)(b.z * scale); v[7] = (__bf16)(b.w * scale);
  return v;
}

// async global->LDS 16B per lane (dest = wave-uniform base + lane*16)
__device__ __forceinline__ void async16(const void* g, void* l) {
  __builtin_amdgcn_global_load_lds(
      (const __attribute__((address_space(1))) void*)g,
      (__attribute__((address_space(3))) void*)l, 16, 0, 0);
}

// ---------------- fp32 -> bf16 conversion (grid-stride, x8) ----------------
__global__ __launch_bounds__(256) void cvt_kernel(
    const float* __restrict__ in, __bf16* __restrict__ outp, int n8)
{
  int i = blockIdx.x * 256 + threadIdx.x;
  const int stride = gridDim.x * 256;
  for (; i < n8; i += stride) {
    const float4* p = (const float4*)(in + (size_t)i * 8);
    float4 a = p[0], b = p[1];
    bf16x8 v;
    v[0] = (__bf16)a.x; v[1] = (__bf16)a.y; v[2] = (__bf16)a.z; v[3] = (__bf16)a.w;
    v[4] = (__bf16)b.x; v[5] = (__bf16)b.y; v[6] = (__bf16)b.z; v[7] = (__bf16)b.w;
    *(bf16x8*)(outp + (size_t)i * 8) = v;
  }
}

// ---------------- fp32 copy (outp <- h2 init for atomic down-GEMM) ----------
__global__ __launch_bounds__(256) void copy_kernel(
    const float* __restrict__ in, float* __restrict__ outp)
{
  const size_t i = ((size_t)blockIdx.x * 256 + threadIdx.x) * 4;
  *(float4*)&outp[i] = *(const float4*)&in[i];
}

// ---------------- GEMM (bf16 operands, dbuf global_load_lds pipeline) -------
// out[m,n] (+)= alpha*colscale[n]*sum_k A[m,k]*W[n,k]; atomic accumulate when gridDim.z>1
// NOTE: all launches use gridDim.x == 16 (M tiles); nwg (x*y) divisible by 8.
__global__ __launch_bounds__(256) void gemm_bf_kernel(
    const __bf16* __restrict__ A, const __bf16* __restrict__ W,
    float* __restrict__ out, const float* __restrict__ addin,
    const float* __restrict__ colscale,
    int N, int K, int ldo, float alpha)
{
  __shared__ __align__(16) __bf16 As[2][128 * 32];   // 8 KB per buf
  __shared__ __align__(16) __bf16 Bs[2][128 * 32];
  const int tid = threadIdx.x;
  const int lane = tid & 63, wave = tid >> 6;
  const int fr = lane & 15, fq = lane >> 4;

  // XCD-aware bijective swizzle: each XCD gets a contiguous chunk of the grid
  const int nwg = (int)(gridDim.x * gridDim.y);
  int lid = (int)(blockIdx.y * gridDim.x + blockIdx.x);
  lid = (lid & 7) * (nwg >> 3) + (lid >> 3);
  const int m0 = (lid & 15) * 128;          // gridDim.x == 16 always
  const int n0 = (lid >> 4) * 128;
  const int wm = (wave >> 1) * 64, wn = (wave & 1) * 64;

  // split-K
  const int KS = K / gridDim.z;
  const int kbase = (int)blockIdx.z * KS;

  // staging: wave w covers rows [w*32, w*32+32) via 2 calls of 16 rows each.
  const int srow = wave * 32 + (lane >> 2);
  const int selem = (lane & 3) * 8;
  const __bf16* ga0 = A + (size_t)(m0 + srow) * K + kbase + selem;
  const __bf16* ga1 = ga0 + (size_t)16 * K;
  int wr0 = n0 + srow;      if (wr0 >= N) wr0 = N - 1;   // clamp (N=4256 tail)
  int wr1 = n0 + srow + 16; if (wr1 >= N) wr1 = N - 1;
  const __bf16* gb0 = W + (size_t)wr0 * K + kbase + selem;
  const __bf16* gb1 = W + (size_t)wr1 * K + kbase + selem;
  const int sbase = wave * 2 * 512;   // element offset of this wave's 1 KB chunk

  floatx4 acc[4][4];
#pragma unroll
  for (int i = 0; i < 4; i++)
#pragma unroll
    for (int j = 0; j < 4; j++) acc[i][j] = (floatx4){0.f, 0.f, 0.f, 0.f};

  // prologue: stage tile 0 into buf 0
  async16(ga0, &As[0][sbase]); async16(ga1, &As[0][sbase + 512]);
  async16(gb0, &Bs[0][sbase]); async16(gb1, &Bs[0][sbase + 512]);
  ga0 += 32; ga1 += 32; gb0 += 32; gb1 += 32;
  __syncthreads();          // drains vmcnt(0): buf0 ready

  const int nsteps = KS >> 5;
  int cur = 0;
  for (int s = 0; s < nsteps - 1; ++s) {
    // prefetch next tile into the other buffer (in flight during compute)
    async16(ga0, &As[cur ^ 1][sbase]); async16(ga1, &As[cur ^ 1][sbase + 512]);
    async16(gb0, &Bs[cur ^ 1][sbase]); async16(gb1, &Bs[cur ^ 1][sbase + 512]);
    ga0 += 32; ga1 += 32; gb0 += 32; gb1 += 32;

    // compute current buffer
    bf16x8 aF[4], bF[4];
#pragma unroll
    for (int i = 0; i < 4; i++)
      aF[i] = *(const bf16x8*)&As[cur][(wm + i * 16 + fr) * 32 + fq * 8];
#pragma unroll
    for (int j = 0; j < 4; j++)
      bF[j] = *(const bf16x8*)&Bs[cur][(wn + j * 16 + fr) * 32 + fq * 8];
#pragma unroll
    for (int i = 0; i < 4; i++)
#pragma unroll
      for (int j = 0; j < 4; j++)
        acc[i][j] = __builtin_amdgcn_mfma_f32_16x16x32_bf16(aF[i], bF[j], acc[i][j], 0, 0, 0);

    __syncthreads();        // drains prefetch vmcnt + all reads of buf cur done
    cur ^= 1;
  }

  // last tile (no prefetch)
  {
    bf16x8 aF[4], bF[4];
#pragma unroll
    for (int i = 0; i < 4; i++)
      aF[i] = *(const bf16x8*)&As[cur][(wm + i * 16 + fr) * 32 + fq * 8];
#pragma unroll
    for (int j = 0; j < 4; j++)
      bF[j] = *(const bf16x8*)&Bs[cur][(wn + j * 16 + fr) * 32 + fq * 8];
#pragma unroll
    for (int i = 0; i < 4; i++)
#pragma unroll
      for (int j = 0; j < 4; j++)
        acc[i][j] = __builtin_amdgcn_mfma_f32_16x16x32_bf16(aF[i], bF[j], acc[i][j], 0, 0, 0);
  }

  const bool at = (gridDim.z > 1);
#pragma unroll
  for (int i = 0; i < 4; i++) {
#pragma unroll
    for (int r = 0; r < 4; r++) {
      const int m = m0 + wm + i * 16 + fq * 4 + r;
      float* orow = out + (size_t)m * ldo;
      const float* arow = addin ? (addin + (size_t)m * ldo) : nullptr;
#pragma unroll
      for (int j = 0; j < 4; j++) {
        const int n = n0 + wn + j * 16 + fr;
        if (n < N) {
          float vv = acc[i][j][r] * alpha;
          if (colscale) vv *= colscale[n];
          if (at) {
            atomicAdd(&orow[n], vv);
          } else {
            if (arow) vv += arow[n];
            orow[n] = vv;
          }
        }
      }
    }
  }
}

// ---------------- RMSNorm (bf16 out + optional fp32 out + residual copy) ----
__global__ __launch_bounds__(256) void rms_kernel(
    const float* __restrict__ in, const float* __restrict__ w,
    __bf16* __restrict__ outb, float* __restrict__ outf, float* __restrict__ copy)
{
  __shared__ float buf[HID];
  __shared__ float red[8];
  const int tid = threadIdx.x;
  const size_t t = blockIdx.x;
  const float* row = in + t * HID;
  float ss = 0.f;
  for (int i = tid; i < HID; i += 256) { float x = row[i]; buf[i] = x; ss += x * x; }
  float tot = block_sum(ss, red);
  float inv = rsqrtf(tot / (float)HID + 1e-5f);
  for (int i = tid; i < HID; i += 256) {
    float x = buf[i];
    float val = x * inv * w[i];
    outb[t * HID + i] = (__bf16)val;
    if (outf) outf[t * HID + i] = val;
    if (copy) copy[t * HID + i] = x;
  }
}

// ---------------- mup column-scale vector ----------------
__global__ void mup_kernel(float* __restrict__ mup) {
  int i = blockIdx.x * 256 + threadIdx.x;
  if (i >= INPROJ_N) return;
  float v = (i < DSSM) ? 1.0f
          : (i < 2 * DSSM) ? 0.9f
          : (i < 2 * DSSM + MS) ? 0.8f
          : (i < 2 * DSSM + 2 * MS) ? 1.1f
          : 1.2f;
  mup[i] = v;
}

// ---------------- RoPE + split qkv (bf16 out; 0.125 softmax scale folded into q)
__global__ __launch_bounds__(256) void rope_kernel(
    const float* __restrict__ qkv, const int* __restrict__ positions,
    __bf16* __restrict__ q, __bf16* __restrict__ k, __bf16* __restrict__ v)
{
  __shared__ float inv_s[32];
  const int tid = threadIdx.x;
  const size_t t = blockIdx.x;
  const int l = (int)(t & (L_ - 1));
  if (tid < 32) inv_s[tid] = powf(1.0e11f, -(float)(2 * tid) / 64.f);
  __syncthreads();
  const float pos = (float)positions[l];
  const float* src = qkv + t * QKV_N;
  for (int idx = tid; idx < 1536; idx += 256) {
    int head = idx >> 5, hd = idx & 31;
    if (head < 32) {
      float ang = pos * inv_s[hd];
      float c = cosf(ang), sn = sinf(ang);
      float x1 = src[head * 64 + hd], x2 = src[head * 64 + 32 + hd];
      __bf16* dst = q + (t * NH + head) * HD;
      dst[hd] = (__bf16)((x1 * c - x2 * sn) * 0.125f);
      dst[hd + 32] = (__bf16)((x2 * c + x1 * sn) * 0.125f);
    } else if (head < 40) {
      int kk = head - 32;
      float ang = pos * inv_s[hd];
      float c = cosf(ang), sn = sinf(ang);
      float x1 = src[2048 + kk * 64 + hd] * 0.7f;
      float x2 = src[2048 + kk * 64 + 32 + hd] * 0.7f;
      __bf16* dst = k + (t * NKV + kk) * HD;
      dst[hd] = (__bf16)(x1 * c - x2 * sn);
      dst[hd + 32] = (__bf16)(x2 * c + x1 * sn);
    } else {
      int vv = head - 40;
      __bf16* dst = v + (t * NKV + vv) * HD;
      dst[hd] = (__bf16)src[2560 + vv * 64 + hd];
      dst[hd + 32] = (__bf16)src[2560 + vv * 64 + 32 + hd];
    }
  }
}

// ---------------- flash attention, bf16 in/out, 64-query tile per block -----
__global__ __launch_bounds__(256) void fattn_kernel(
    const __bf16* __restrict__ q, const __bf16* __restrict__ k,
    const __bf16* __restrict__ v, __bf16* __restrict__ out)
{
  __shared__ __align__(16) __bf16 Vt[64][72];      // [dim][key]
  __shared__ __align__(16) __bf16 Ps[4][16][72];   // per-wave P strip [q16][key]
  const int tid = threadIdx.x;
  const int wave = tid >> 6, lane = tid & 63;
  const int fr = lane & 15, fq = lane >> 4;
  const int qt = (int)(gridDim.x - 1) - blockIdx.x;   // big tiles dispatch first
  const int h = blockIdx.y, b = blockIdx.z, g = h >> 2;
  const int l0 = qt * 64;

  bf16x8 qf[2];
  {
    const int qrow = l0 + wave * 16 + fr;
    const __bf16* qp = q + (((size_t)(b * L_ + qrow)) * NH + h) * HD;
    qf[0] = *(const bf16x8*)&qp[fq * 8];
    qf[1] = *(const bf16x8*)&qp[32 + fq * 8];
  }

  floatx4 O[4];
  float m_run[4], l_run[4];
#pragma unroll
  for (int i = 0; i < 4; i++) { O[i] = (floatx4){0.f,0.f,0.f,0.f}; m_run[i] = -3.0e38f; l_run[i] = 0.f; }

  for (int kt = 0; kt <= qt; kt++) {
    __syncthreads();
#pragma unroll
    for (int pp = 0; pp < 4; pp++) {
      const int kb = pp * 4 + wave;
      bf16x4 pk;
#pragma unroll
      for (int c = 0; c < 4; c++)
        pk[c] = v[(((size_t)(b * L_ + kt * 64 + kb * 4 + c)) * NKV + g) * HD + lane];
      *(bf16x4*)&Vt[lane][kb * 4] = pk;
    }

    floatx4 S[4];
#pragma unroll
    for (int j = 0; j < 4; j++) {
      const __bf16* kp = k + (((size_t)(b * L_ + kt * 64 + j * 16 + fr)) * NKV + g) * HD;
      floatx4 sa = (floatx4){0.f,0.f,0.f,0.f};
#pragma unroll
      for (int s = 0; s < 2; s++) {
        bf16x8 kf = *(const bf16x8*)&kp[s * 32 + fq * 8];
        sa = __builtin_amdgcn_mfma_f32_16x16x32_bf16(qf[s], kf, sa, 0, 0, 0);
      }
      S[j] = sa;
    }

    if (kt == qt) {
      const int qbase = wave * 16 + fq * 4;
#pragma unroll
      for (int j = 0; j < 4; j++)
#pragma unroll
        for (int r = 0; r < 4; r++)
          if (j * 16 + fr > qbase + r) S[j][r] = -1.0e30f;
    }

    float rm[4], alpha[4], rsum[4];
#pragma unroll
    for (int r = 0; r < 4; r++)
      rm[r] = fmaxf(fmaxf(S[0][r], S[1][r]), fmaxf(S[2][r], S[3][r]));
#pragma unroll
    for (int msk = 1; msk <= 8; msk <<= 1)
#pragma unroll
      for (int r = 0; r < 4; r++) rm[r] = fmaxf(rm[r], __shfl_xor(rm[r], msk, 64));
#pragma unroll
    for (int r = 0; r < 4; r++) {
      float mnew = fmaxf(m_run[r], rm[r]);
      alpha[r] = __expf(m_run[r] - mnew);
      m_run[r] = mnew;
    }
#pragma unroll
    for (int j = 0; j < 4; j++)
#pragma unroll
      for (int r = 0; r < 4; r++) S[j][r] = __expf(S[j][r] - m_run[r]);
#pragma unroll
    for (int r = 0; r < 4; r++)
      rsum[r] = S[0][r] + S[1][r] + S[2][r] + S[3][r];
#pragma unroll
    for (int msk = 1; msk <= 8; msk <<= 1)
#pragma unroll
      for (int r = 0; r < 4; r++) rsum[r] += __shfl_xor(rsum[r], msk, 64);
#pragma unroll
    for (int r = 0; r < 4; r++) l_run[r] = l_run[r] * alpha[r] + rsum[r];
#pragma unroll
    for (int d4 = 0; d4 < 4; d4++)
#pragma unroll
      for (int r = 0; r < 4; r++) O[d4][r] *= alpha[r];

#pragma unroll
    for (int j = 0; j < 4; j++)
#pragma unroll
      for (int r = 0; r < 4; r++)
        Ps[wave][fq * 4 + r][j * 16 + fr] = (__bf16)S[j][r];

    __syncthreads();

#pragma unroll
    for (int s = 0; s < 2; s++) {
      bf16x8 pf = *(const bf16x8*)&Ps[wave][fr][s * 32 + fq * 8];
#pragma unroll
      for (int d4 = 0; d4 < 4; d4++) {
        bf16x8 vf = *(const bf16x8*)&Vt[d4 * 16 + fr][s * 32 + fq * 8];
        O[d4] = __builtin_amdgcn_mfma_f32_16x16x32_bf16(pf, vf, O[d4], 0, 0, 0);
      }
    }
  }

  float rl[4];
#pragma unroll
  for (int r = 0; r < 4; r++) rl[r] = 1.f / l_run[r];
#pragma unroll
  for (int d4 = 0; d4 < 4; d4++)
#pragma unroll
    for (int r = 0; r < 4; r++) {
      const int qg = l0 + wave * 16 + fq * 4 + r;
      out[((size_t)(b * L_ + qg)) * HID + h * 64 + d4 * 16 + fr] = (__bf16)(O[d4][r] * rl[r]);
    }
}

// ---------------- exact-fp32 recompute of the 32 dt columns of in_proj ------
__global__ __launch_bounds__(256) void dtfix_kernel(
    const float* __restrict__ hs_ln, const float* __restrict__ w, float* __restrict__ proj)
{
  const size_t t = blockIdx.x;
  const int tid = threadIdx.x;
  const int o = tid >> 3, part = tid & 7;
  const float* a = hs_ln + t * HID;
  const float* wr = w + (size_t)(INPROJ_N - MH + o) * HID;
  float s = 0.f;
  for (int kk = part * 4; kk < HID; kk += 32) {
    const float4 av = *(const float4*)&a[kk];
    const float4 wv = *(const float4*)&wr[kk];
    s += av.x * wv.x + av.y * wv.y + av.z * wv.z + av.w * wv.w;
  }
  s += __shfl_xor(s, 1);
  s += __shfl_xor(s, 2);
  s += __shfl_xor(s, 4);
  if (part == 0) proj[t * INPROJ_N + (INPROJ_N - MH) + o] = s * 1.32f; // SSM_IN*mup_dt
}

// ---------------- depthwise causal conv (MK=4) + bias + silu ----------------
__global__ __launch_bounds__(256) void conv_kernel(
    const float* __restrict__ proj, const float* __restrict__ cw,
    const float* __restrict__ cb, float* __restrict__ xbc)
{
  const int c = blockIdx.x * 256 + threadIdx.x;
  if (c >= CONV_DIM) return;
  const int t = blockIdx.y;
  const int l = t & (L_ - 1);
  float acc = cb[c];
#pragma unroll
  for (int kk = 0; kk < MK; kk++) {
    int lp = l - (MK - 1) + kk;
    if (lp >= 0)
      acc += proj[((size_t)(t - (MK - 1) + kk)) * INPROJ_N + DSSM + c] * cw[c * MK + kk];
  }
  xbc[(size_t)t * CONV_DIM + c] = acc / (1.f + __expf(-acc));
}

// ---------------- chunked Mamba2 scan, stage A: intra-chunk (MFMA) ----------
__global__ __launch_bounds__(256) void scanA_kernel(
    const float* __restrict__ xbc, const float* __restrict__ proj,
    const float* __restrict__ A_log, const float* __restrict__ dt_bias,
    const float* __restrict__ Dp,
    float* __restrict__ y, float* __restrict__ Tbuf,
    float* __restrict__ lam, float* __restrict__ dec)
{
  __shared__ __align__(16) __bf16 xT[64][72];    // [p][l]
  __shared__ __align__(16) __bf16 BTw[64][72];   // [s][l] (scaled)
  __shared__ __align__(16) __bf16 Braw[64][72];  // [l][s]
  __shared__ __align__(16) __bf16 Craw[64][72];  // [l][s]
  __shared__ __align__(16) __bf16 Ps[4][16][72]; // per-wave M strip
  __shared__ float dt_s[64], cum_s[64];

  const int tid = threadIdx.x;
  const int lane = tid & 63, wave = tid >> 6;
  const int fr = lane & 15, fq = lane >> 4;
  const int c = blockIdx.x, h = blockIdx.y, b = blockIdx.z;
  const int t0 = b * L_ + c * CL;
  const float Ah = -expf(A_log[h]);
  const float dtb = dt_bias[h], Dh = Dp[h];

  if (wave == 0) {
    float draw = proj[(size_t)(t0 + lane) * INPROJ_N + (INPROJ_N - MH) + h];
    float dtv = draw + dtb;
    dtv = (dtv > 20.f) ? dtv : log1pf(__expf(dtv));
    float cs = dtv * Ah;
#pragma unroll
    for (int d = 1; d < 64; d <<= 1) {
      float nv = __shfl_up(cs, d, 64);
      if (lane >= d) cs += nv;
    }
    dt_s[lane] = dtv;
    cum_s[lane] = cs;
  }

#pragma unroll
  for (int pass = 0; pass < 4; pass++) {
    const int l = pass * 16 + (tid >> 4);
    const int s4 = (tid & 15) * 4;
    const float* rowp = xbc + (size_t)(t0 + l) * CONV_DIM;
    float4 xv = *(const float4*)&rowp[h * 64 + s4];
    float4 bv = *(const float4*)&rowp[DSSM + s4];
    float4 cv = *(const float4*)&rowp[DSSM + MS + s4];
    xT[s4 + 0][l] = (__bf16)xv.x;
    xT[s4 + 1][l] = (__bf16)xv.y;
    xT[s4 + 2][l] = (__bf16)xv.z;
    xT[s4 + 3][l] = (__bf16)xv.w;
    bf16x4 b4; b4[0]=(__bf16)bv.x; b4[1]=(__bf16)bv.y; b4[2]=(__bf16)bv.z; b4[3]=(__bf16)bv.w;
    *(bf16x4*)&Braw[l][s4] = b4;
    bf16x4 c4; c4[0]=(__bf16)cv.x; c4[1]=(__bf16)cv.y; c4[2]=(__bf16)cv.z; c4[3]=(__bf16)cv.w;
    *(bf16x4*)&Craw[l][s4] = c4;
  }
  __syncthreads();

  const float cend = cum_s[63];
#pragma unroll
  for (int pass = 0; pass < 4; pass++) {
    const int l = pass * 16 + (tid >> 4);
    const int s4 = (tid & 15) * 4;
    const float wl = __expf(cend - cum_s[l]) * dt_s[l];
    float4 bv = *(const float4*)&xbc[(size_t)(t0 + l) * CONV_DIM + DSSM + s4];
    BTw[s4 + 0][l] = (__bf16)(bv.x * wl);
    BTw[s4 + 1][l] = (__bf16)(bv.y * wl);
    BTw[s4 + 2][l] = (__bf16)(bv.z * wl);
    BTw[s4 + 3][l] = (__bf16)(bv.w * wl);
  }

  {
    bf16x8 aF0 = *(const bf16x8*)&Craw[wave * 16 + fr][fq * 8];
    bf16x8 aF1 = *(const bf16x8*)&Craw[wave * 16 + fr][fq * 8 + 32];
#pragma unroll
    for (int j = 0; j < 4; j++) {
      floatx4 s = (floatx4){0.f,0.f,0.f,0.f};
      bf16x8 b0 = *(const bf16x8*)&Braw[j * 16 + fr][fq * 8];
      bf16x8 b1 = *(const bf16x8*)&Braw[j * 16 + fr][fq * 8 + 32];
      s = __builtin_amdgcn_mfma_f32_16x16x32_bf16(aF0, b0, s, 0, 0, 0);
      s = __builtin_amdgcn_mfma_f32_16x16x32_bf16(aF1, b1, s, 0, 0, 0);
      const int m = j * 16 + fr;
      const float dtm = dt_s[m], cmm = cum_s[m];
#pragma unroll
      for (int r = 0; r < 4; r++) {
        const int lR = wave * 16 + fq * 4 + r;
        float f = (m <= lR) ? __expf(cum_s[lR] - cmm) * dtm : 0.f;
        Ps[wave][fq * 4 + r][m] = (__bf16)(s[r] * f);
      }
    }
  }
  __syncthreads();

  {
    bf16x8 aF0 = *(const bf16x8*)&Ps[wave][fr][fq * 8];
    bf16x8 aF1 = *(const bf16x8*)&Ps[wave][fr][fq * 8 + 32];
#pragma unroll
    for (int j = 0; j < 4; j++) {
      floatx4 s = (floatx4){0.f,0.f,0.f,0.f};
      bf16x8 b0 = *(const bf16x8*)&xT[j * 16 + fr][fq * 8];
      bf16x8 b1 = *(const bf16x8*)&xT[j * 16 + fr][fq * 8 + 32];
      s = __builtin_amdgcn_mfma_f32_16x16x32_bf16(aF0, b0, s, 0, 0, 0);
      s = __builtin_amdgcn_mfma_f32_16x16x32_bf16(aF1, b1, s, 0, 0, 0);
      const int p = j * 16 + fr;
#pragma unroll
      for (int r = 0; r < 4; r++) {
        const int lR = wave * 16 + fq * 4 + r;
        float xval = (float)xT[p][lR];
        y[(size_t)(t0 + lR) * DSSM + h * 64 + p] = s[r] + Dh * xval;
      }
    }
  }

  {
    float* Tb = Tbuf + ((size_t)((b * MH + h) * CH + c)) * 4096;
    bf16x8 aF0 = *(const bf16x8*)&xT[wave * 16 + fr][fq * 8];
    bf16x8 aF1 = *(const bf16x8*)&xT[wave * 16 + fr][fq * 8 + 32];
#pragma unroll
    for (int j = 0; j < 4; j++) {
      floatx4 s = (floatx4){0.f,0.f,0.f,0.f};
      bf16x8 b0 = *(const bf16x8*)&BTw[j * 16 + fr][fq * 8];
      bf16x8 b1 = *(const bf16x8*)&BTw[j * 16 + fr][fq * 8 + 32];
      s = __builtin_amdgcn_mfma_f32_16x16x32_bf16(aF0, b0, s, 0, 0, 0);
      s = __builtin_amdgcn_mfma_f32_16x16x32_bf16(aF1, b1, s, 0, 0, 0);
#pragma unroll
      for (int r = 0; r < 4; r++)
        Tb[(wave * 16 + fq * 4 + r) * 64 + j * 16 + fr] = s[r];
    }
  }

  if (tid == 0) lam[(b * MH + h) * CH + c] = __expf(cend);
  if (tid >= 64 && tid < 128)
    dec[((size_t)((b * MH + h) * CH + c)) * 64 + (tid - 64)] = __expf(cum_s[tid - 64]);
}

// ---------------- chunked scan, stage B: inter-chunk state scan -------------
__global__ __launch_bounds__(256) void scanB_kernel(
    const float* __restrict__ xbc, const float* __restrict__ Tbuf,
    const float* __restrict__ lam, const float* __restrict__ dec,
    float* __restrict__ y)
{
  __shared__ __align__(16) float S[64][68];
  __shared__ __align__(16) __bf16 Cc[64][72];
  __shared__ float decl[64];
  const int tid = threadIdx.x;
  const int lane = tid & 63, wave = tid >> 6;
  const int fr = lane & 15, fq = lane >> 4;
  const int h = blockIdx.x, b = blockIdx.y;

  const int sown = tid & 63, pbase = (tid >> 6) * 16;
#pragma unroll
  for (int i = 0; i < 16; i++) S[pbase + i][sown] = 0.f;
  __syncthreads();

  for (int c = 0; c < CH; c++) {
    const int t0 = b * L_ + c * CL;
#pragma unroll
    for (int pass = 0; pass < 4; pass++) {
      const int l = pass * 16 + (tid >> 4);
      const int s4 = (tid & 15) * 4;
      float4 cv = *(const float4*)&xbc[(size_t)(t0 + l) * CONV_DIM + DSSM + MS + s4];
      bf16x4 c4; c4[0]=(__bf16)cv.x; c4[1]=(__bf16)cv.y; c4[2]=(__bf16)cv.z; c4[3]=(__bf16)cv.w;
      *(bf16x4*)&Cc[l][s4] = c4;
    }
    if (tid < 64) decl[tid] = dec[((size_t)((b * MH + h) * CH + c)) * 64 + tid];
    __syncthreads();

    if (c > 0) {
      bf16x8 aF0 = *(const bf16x8*)&Cc[wave * 16 + fr][fq * 8];
      bf16x8 aF1 = *(const bf16x8*)&Cc[wave * 16 + fr][fq * 8 + 32];
#pragma unroll
      for (int j = 0; j < 4; j++) {
        const float* srow = &S[j * 16 + fr][0];
        float4 s0 = *(const float4*)&srow[fq * 8];
        float4 s1 = *(const float4*)&srow[fq * 8 + 4];
        float4 s2 = *(const float4*)&srow[fq * 8 + 32];
        float4 s3 = *(const float4*)&srow[fq * 8 + 36];
        bf16x8 b0 = pack8(s0, s1, 1.f);
        bf16x8 b1 = pack8(s2, s3, 1.f);
        floatx4 acc = (floatx4){0.f,0.f,0.f,0.f};
        acc = __builtin_amdgcn_mfma_f32_16x16x32_bf16(aF0, b0, acc, 0, 0, 0);
        acc = __builtin_amdgcn_mfma_f32_16x16x32_bf16(aF1, b1, acc, 0, 0, 0);
        const int p = j * 16 + fr;
#pragma unroll
        for (int r = 0; r < 4; r++) {
          const int lR = wave * 16 + fq * 4 + r;
          float* yp = &y[(size_t)(t0 + lR) * DSSM + h * 64 + p];
          *yp += decl[lR] * acc[r];
        }
      }
    }
    __syncthreads();

    const float lc = lam[(b * MH + h) * CH + c];
    const float* Tb = Tbuf + ((size_t)((b * MH + h) * CH + c)) * 4096;
#pragma unroll
    for (int i = 0; i < 16; i++) {
      float tv = Tb[(pbase + i) * 64 + sown];
      S[pbase + i][sown] = lc * S[pbase + i][sown] + tv;
    }
    __syncthreads();
  }
}

// ---------------- gating (y * silu(z)) + RMSNorm -> bf16 ----------------
__global__ __launch_bounds__(256) void gating_kernel(
    const float* __restrict__ y, const float* __restrict__ proj,
    const float* __restrict__ nw, __bf16* __restrict__ g)
{
  __shared__ float buf[DSSM];
  __shared__ float red[8];
  const int tid = threadIdx.x;
  const size_t t = blockIdx.x;
  float ss = 0.f;
  for (int i = tid; i < DSSM; i += 256) {
    float zv = proj[t * INPROJ_N + i];
    float yv = y[t * DSSM + i];
    float gv = yv * zv / (1.f + __expf(-zv));
    buf[i] = gv;
    ss += gv * gv;
  }
  float tot = block_sum(ss, red);
  float inv = rsqrtf(tot / (float)DSSM + 1e-5f);
  for (int i = tid; i < DSSM; i += 256) g[t * DSSM + i] = (__bf16)(buf[i] * inv * nw[i]);
}

// ---------------- SwiGLU activation -> bf16 (x4 vectorized) ----------------
__global__ __launch_bounds__(256) void act_kernel(
    const float* __restrict__ gu, __bf16* __restrict__ act)
{
  const int i = (blockIdx.x * 256 + threadIdx.x) * 4;
  const size_t t = blockIdx.y;
  float4 g4 = *(const float4*)&gu[t * (2 * INTER) + i];
  float4 u4 = *(const float4*)&gu[t * (2 * INTER) + INTER + i];
  bf16x4 o;
  float gt;
  gt = g4.x * 0.9f; o[0] = (__bf16)(gt / (1.f + __expf(-gt)) * u4.x);
  gt = g4.y * 0.9f; o[1] = (__bf16)(gt / (1.f + __expf(-gt)) * u4.y);
  gt = g4.z * 0.9f; o[2] = (__bf16)(gt / (1.f + __expf(-gt)) * u4.z);
  gt = g4.w * 0.9f; o[3] = (__bf16)(gt / (1.f + __expf(-gt)) * u4.w);
  *(bf16x4*)&act[t * INTER + i] = o;
}

// ---------------- launcher ----------------
extern "C" void kernel_launch(void* const* d_in, const int* in_sizes, int n_in,
                              void* d_out, int out_size, void* d_ws, size_t ws_size,
                              hipStream_t stream)
{
  const float* hidden      = (const float*)d_in[0];
  const int*   positions   = (const int*)d_in[1];
  const float* w_in_ln     = (const float*)d_in[2];
  const float* qkv_w       = (const float*)d_in[3];
  const float* o_w         = (const float*)d_in[4];
  const float* in_proj_w   = (const float*)d_in[5];
  const float* conv_w      = (const float*)d_in[6];
  const float* conv_b      = (const float*)d_in[7];
  const float* A_log       = (const float*)d_in[8];
  const float* dt_bias     = (const float*)d_in[9];
  const float* Dp          = (const float*)d_in[10];
  const float* ssm_norm_w  = (const float*)d_in[11];
  const float* out_proj_w  = (const float*)d_in[12];
  const float* w_pre_ff_ln = (const float*)d_in[13];
  const float* gate_up_w   = (const float*)d_in[14];
  const float* down_w      = (const float*)d_in[15];
  (void)in_sizes; (void)n_in; (void)out_size; (void)ws_size;

  float* ws   = (float*)d_ws;
  float* outp = (float*)d_out;

  float*  h2    = ws + OFF_H2;
  float*  mup   = ws + OFF_MUP;
  __bf16* wqkv  = (__bf16*)(ws + OFF_WQKV);
  __bf16* win   = (__bf16*)(ws + OFF_WIN);
  __bf16* wo    = (__bf16*)(ws + OFF_WO);
  __bf16* wop   = (__bf16*)(ws + OFF_WOP);
  __bf16* hsb   = (__bf16*)(ws + OFF_HSB);
  float*  hsf   = ws + OFF_HSF;
  float*  qkv   = ws + OFF_QKV;
  __bf16* qb    = (__bf16*)(ws + OFF_Q);
  __bf16* kb    = (__bf16*)(ws + OFF_K);
  __bf16* vb    = (__bf16*)(ws + OFF_V);
  __bf16* attb  = (__bf16*)(ws + OFF_ATT);
  float*  proj  = ws + OFF_PROJ;
  float*  xbc   = ws + OFF_XBC;
  float*  y     = ws + OFF_Y;
  __bf16* gb    = (__bf16*)(ws + OFF_G);
  float*  Tbuf  = ws + OFF_TB;
  float*  dec   = ws + OFF_DEC;
  float*  lam   = ws + OFF_LAM;
  __bf16* hs2b  = (__bf16*)(ws + OFF_HS2B);
  float*  gu    = ws + OFF_GU;
  __bf16* actb  = (__bf16*)(ws + OFF_ACTB);
  __bf16* wb2   = (__bf16*)(ws + OFF_WB2);

  // phase-1 weight conversions (fp32 -> bf16)
  cvt_kernel<<<2048, 256, 0, stream>>>(qkv_w, wqkv, 786432);
  cvt_kernel<<<2048, 256, 0, stream>>>(in_proj_w, win, 1089536);
  cvt_kernel<<<2048, 256, 0, stream>>>(o_w, wo, 524288);
  cvt_kernel<<<2048, 256, 0, stream>>>(out_proj_w, wop, 524288);
  mup_kernel<<<17, 256, 0, stream>>>(mup);
  rms_kernel<<<T_, 256, 0, stream>>>(hidden, w_in_ln, hsb, hsf, h2);

  // attention branch
  gemm_bf_kernel<<<dim3(16, 24, 1), 256, 0, stream>>>(hsb, wqkv, qkv, nullptr, nullptr,
                                                      QKV_N, HID, QKV_N, 1.2f);
  rope_kernel<<<T_, 256, 0, stream>>>(qkv, positions, qb, kb, vb);
  fattn_kernel<<<dim3(L_ / 64, NH, B_), 256, 0, stream>>>(qb, kb, vb, attb);
  gemm_bf_kernel<<<dim3(16, 16, 4), 256, 0, stream>>>(attb, wo, h2, nullptr, nullptr,
                                                      HID, HID, HID, 0.8f);   // atomic += into residual

  // mamba branch
  gemm_bf_kernel<<<dim3(16, 34, 1), 256, 0, stream>>>(hsb, win, proj, nullptr, mup,
                                                      INPROJ_N, HID, INPROJ_N, 1.1f);
  dtfix_kernel<<<T_, 256, 0, stream>>>(hsf, in_proj_w, proj);
  conv_kernel<<<dim3(9, T_), 256, 0, stream>>>(proj, conv_w, conv_b, xbc);
  scanA_kernel<<<dim3(CH, MH, B_), 256, 0, stream>>>(xbc, proj, A_log, dt_bias, Dp,
                                                     y, Tbuf, lam, dec);
  scanB_kernel<<<dim3(MH, B_), 256, 0, stream>>>(xbc, Tbuf, lam, dec, y);
  gating_kernel<<<T_, 256, 0, stream>>>(y, proj, ssm_norm_w, gb);
  gemm_bf_kernel<<<dim3(16, 16, 4), 256, 0, stream>>>(gb, wop, h2, nullptr, nullptr,
                                                      HID, HID, HID, 0.9f);   // atomic += into residual

  // MLP (wb2 time-shared: gate half -> up half -> down_w)
  rms_kernel<<<T_, 256, 0, stream>>>(h2, w_pre_ff_ln, hs2b, nullptr, nullptr);
  cvt_kernel<<<2048, 256, 0, stream>>>(gate_up_w, wb2, 2097152);
  gemm_bf_kernel<<<dim3(16, 64, 1), 256, 0, stream>>>(hs2b, wb2, gu, nullptr, nullptr,
                                                      INTER, HID, 2 * INTER, 1.0f);
  cvt_kernel<<<2048, 256, 0, stream>>>(gate_up_w + (size_t)INTER * HID, wb2, 2097152);
  gemm_bf_kernel<<<dim3(16, 64, 1), 256, 0, stream>>>(hs2b, wb2, gu + INTER, nullptr, nullptr,
                                                      INTER, HID, 2 * INTER, 1.0f);
  act_kernel<<<dim3(INTER / 1024, T_), 256, 0, stream>>>(gu, actb);
  cvt_kernel<<<2048, 256, 0, stream>>>(down_w, wb2, 2097152);
  copy_kernel<<<4096, 256, 0, stream>>>(h2, outp);
  gemm_bf_kernel<<<dim3(16, 16, 4), 256, 0, stream>>>(actb, wb2, outp, nullptr, nullptr,
                                                      HID, INTER, HID, 0.8f); // atomic += onto residual copy
}

// Round 3
// 1191.051 us; speedup vs baseline: 1.4040x; 1.0621x over previous
//
#include <hip/hip_runtime.h>
#include <hip/hip_bf16.h>
#include <math.h>

// ---------------- problem constants ----------------
#define B_      2
#define L_      1024
#define HID     2048
#define T_      (B_*L_)      // 2048 tokens
#define NH      32
#define HD      64
#define NKV     8
#define INTER   8192
#define DSSM    2048
#define MH      32
#define MP      64
#define MS      64
#define MK      4
#define CONV_DIM 2176
#define QKV_N   3072
#define INPROJ_N 4256
#define CH      16     // scan chunks
#define CL      64     // chunk length

typedef __bf16 bf16x8 __attribute__((ext_vector_type(8)));
typedef __bf16 bf16x4 __attribute__((ext_vector_type(4)));
typedef float  floatx4 __attribute__((ext_vector_type(4)));

// ---------------- workspace layout (float elements) ----------------
// persistent
static const size_t OFF_H2   = 0;                       // 4,194,304 residual stream (fp32)
static const size_t OFF_MUP  = 4194304;                 // 16,384 slot
static const size_t AR       = 4210688;                 // arena base
// phase 1
static const size_t OFF_WQKV = AR;                      // bf16 6,291,456 el = 3,145,728 fl
static const size_t OFF_WIN  = OFF_WQKV + 3145728;      // bf16 8,716,288 el = 4,358,144 fl
static const size_t OFF_WO   = OFF_WIN  + 4358144;      // bf16 4,194,304 el = 2,097,152 fl
static const size_t OFF_WOP  = OFF_WO   + 2097152;      // bf16 4,194,304 el = 2,097,152 fl
static const size_t OFF_HSB  = OFF_WOP  + 2097152;      // bf16 hs_ln
static const size_t OFF_HSF  = OFF_HSB  + 2097152;      // fp32 hs_ln (dtfix)
static const size_t OFF_QKV  = OFF_HSF  + 4194304;      // fp32 6,291,456
static const size_t OFF_Q    = OFF_QKV  + 6291456;      // bf16 4,194,304 el
static const size_t OFF_K    = OFF_Q    + 2097152;      // bf16 1,048,576 el
static const size_t OFF_V    = OFF_K    + 524288;       // bf16 1,048,576 el
static const size_t OFF_ATT  = OFF_V    + 524288;       // bf16 4,194,304 el
static const size_t OFF_PROJ = OFF_ATT  + 2097152;      // fp32 8,716,288
static const size_t OFF_XBC  = OFF_PROJ + 8716288;      // fp32 4,456,448
static const size_t OFF_Y    = OFF_XBC  + 4456448;      // fp32 4,194,304
static const size_t OFF_G    = OFF_Y    + 4194304;      // bf16 4,194,304 el
// scan scratch aliases (qkv/q/v dead by scan time)
static const size_t OFF_TB   = OFF_QKV;                 // fp32 4,194,304 (Tbuf)
static const size_t OFF_DEC  = OFF_Q;                   // fp32 65,536
static const size_t OFF_LAM  = OFF_V;                   // fp32 1,024
// phase 2 (aliases phase-1 arena; everything above dead by MLP)
static const size_t OFF_HS2B = AR;                      // bf16 4,194,304 el
static const size_t OFF_GU   = AR + 2097152;            // fp32 33,554,432
static const size_t OFF_ACTB = OFF_GU + 33554432;       // bf16 16,777,216 el
static const size_t OFF_WB2  = OFF_ACTB + 8388608;      // bf16 16,777,216 el (gate/up/down_w time-shared)
// total = AR + 52,428,800 = 56,639,488 floats = 226.6 MB

// ---------------- helpers ----------------
__device__ inline float block_sum(float v, float* red) {
#pragma unroll
  for (int o = 32; o > 0; o >>= 1) v += __shfl_down(v, o, 64);
  const int lane = threadIdx.x & 63, wv = threadIdx.x >> 6;
  if (lane == 0) red[wv] = v;
  __syncthreads();
  if (threadIdx.x == 0) red[0] = red[0] + red[1] + red[2] + red[3];
  __syncthreads();
  float r = red[0];
  __syncthreads();
  return r;
}

__device__ inline bf16x8 pack8(float4 a, float4 b, float scale) {
  bf16x8 v;
  v[0] = (__bf16)(a.x * scale); v[1] = (__bf16)(a.y * scale);
  v[2] = (__bf16)(a.z * scale); v[3] = (__bf16)(a.w * scale);
  v[4] = (__bf16)(b.x * scale); v[5] = (__bf16)(b.y * scale);
  v[6] = (__bf16)(b.z * scale); v[7] = (__bf16)(b.w * scale);
  return v;
}

// async global->LDS 16B per lane (dest = wave-uniform base + lane*16)
__device__ __forceinline__ void async16(const void* g, void* l) {
  __builtin_amdgcn_global_load_lds(
      (const __attribute__((address_space(1))) void*)g,
      (__attribute__((address_space(3))) void*)l, 16, 0, 0);
}

// ---------------- fp32 -> bf16 conversion (grid-stride, x8) ----------------
__global__ __launch_bounds__(256) void cvt_kernel(
    const float* __restrict__ in, __bf16* __restrict__ outp, int n8)
{
  int i = blockIdx.x * 256 + threadIdx.x;
  const int stride = gridDim.x * 256;
  for (; i < n8; i += stride) {
    const float4* p = (const float4*)(in + (size_t)i * 8);
    float4 a = p[0], b = p[1];
    bf16x8 v;
    v[0] = (__bf16)a.x; v[1] = (__bf16)a.y; v[2] = (__bf16)a.z; v[3] = (__bf16)a.w;
    v[4] = (__bf16)b.x; v[5] = (__bf16)b.y; v[6] = (__bf16)b.z; v[7] = (__bf16)b.w;
    *(bf16x8*)(outp + (size_t)i * 8) = v;
  }
}

// ---------------- fp32 copy (outp <- h2 init for atomic down-GEMM) ----------
__global__ __launch_bounds__(256) void copy_kernel(
    const float* __restrict__ in, float* __restrict__ outp)
{
  const size_t i = ((size_t)blockIdx.x * 256 + threadIdx.x) * 4;
  *(float4*)&outp[i] = *(const float4*)&in[i];
}

// ---------------- GEMM 128x128 (bf16, dbuf global_load_lds) — qkv / in_proj -
// out[m,n] (+)= alpha*colscale[n]*sum_k A[m,k]*W[n,k]; atomic when gridDim.z>1
// gridDim.x == 16 (M tiles); nwg (x*y) divisible by 8.
__global__ __launch_bounds__(256) void gemm_bf_kernel(
    const __bf16* __restrict__ A, const __bf16* __restrict__ W,
    float* __restrict__ out, const float* __restrict__ colscale,
    int N, int K, int ldo, float alpha)
{
  __shared__ __align__(16) __bf16 As[2][128 * 32];
  __shared__ __align__(16) __bf16 Bs[2][128 * 32];
  const int tid = threadIdx.x;
  const int lane = tid & 63, wave = tid >> 6;
  const int fr = lane & 15, fq = lane >> 4;

  const int nwg = (int)(gridDim.x * gridDim.y);
  int lid = (int)(blockIdx.y * gridDim.x + blockIdx.x);
  lid = (lid & 7) * (nwg >> 3) + (lid >> 3);
  const int m0 = (lid & 15) * 128;
  const int n0 = (lid >> 4) * 128;
  const int wm = (wave >> 1) * 64, wn = (wave & 1) * 64;

  const int KS = K / gridDim.z;
  const int kbase = (int)blockIdx.z * KS;

  const int srow = wave * 32 + (lane >> 2);
  const int selem = (lane & 3) * 8;
  const __bf16* ga0 = A + (size_t)(m0 + srow) * K + kbase + selem;
  const __bf16* ga1 = ga0 + (size_t)16 * K;
  int wr0 = n0 + srow;      if (wr0 >= N) wr0 = N - 1;
  int wr1 = n0 + srow + 16; if (wr1 >= N) wr1 = N - 1;
  const __bf16* gb0 = W + (size_t)wr0 * K + kbase + selem;
  const __bf16* gb1 = W + (size_t)wr1 * K + kbase + selem;
  const int sbase = wave * 2 * 512;

  floatx4 acc[4][4];
#pragma unroll
  for (int i = 0; i < 4; i++)
#pragma unroll
    for (int j = 0; j < 4; j++) acc[i][j] = (floatx4){0.f, 0.f, 0.f, 0.f};

  async16(ga0, &As[0][sbase]); async16(ga1, &As[0][sbase + 512]);
  async16(gb0, &Bs[0][sbase]); async16(gb1, &Bs[0][sbase + 512]);
  ga0 += 32; ga1 += 32; gb0 += 32; gb1 += 32;
  __syncthreads();

  const int nsteps = KS >> 5;
  int cur = 0;
  for (int s = 0; s < nsteps; ++s) {
    if (s + 1 < nsteps) {
      async16(ga0, &As[cur ^ 1][sbase]); async16(ga1, &As[cur ^ 1][sbase + 512]);
      async16(gb0, &Bs[cur ^ 1][sbase]); async16(gb1, &Bs[cur ^ 1][sbase + 512]);
      ga0 += 32; ga1 += 32; gb0 += 32; gb1 += 32;
    }
    bf16x8 aF[4], bF[4];
#pragma unroll
    for (int i = 0; i < 4; i++)
      aF[i] = *(const bf16x8*)&As[cur][(wm + i * 16 + fr) * 32 + fq * 8];
#pragma unroll
    for (int j = 0; j < 4; j++)
      bF[j] = *(const bf16x8*)&Bs[cur][(wn + j * 16 + fr) * 32 + fq * 8];
#pragma unroll
    for (int i = 0; i < 4; i++)
#pragma unroll
      for (int j = 0; j < 4; j++)
        acc[i][j] = __builtin_amdgcn_mfma_f32_16x16x32_bf16(aF[i], bF[j], acc[i][j], 0, 0, 0);
    __syncthreads();
    cur ^= 1;
  }

  const bool at = (gridDim.z > 1);
#pragma unroll
  for (int i = 0; i < 4; i++) {
#pragma unroll
    for (int r = 0; r < 4; r++) {
      const int m = m0 + wm + i * 16 + fq * 4 + r;
      float* orow = out + (size_t)m * ldo;
#pragma unroll
      for (int j = 0; j < 4; j++) {
        const int n = n0 + wn + j * 16 + fr;
        if (n < N) {
          float vv = acc[i][j][r] * alpha;
          if (colscale) vv *= colscale[n];
          if (at) atomicAdd(&orow[n], vv);
          else    orow[n] = vv;
        }
      }
    }
  }
}

// ---------------- GEMM 256x256 (bf16, BK=64, 8 waves, dbuf) — big GEMMs -----
// grid (8, Ntiles, z); 512 threads; 128 KiB LDS -> 1 block/CU.
// out[m,n] (+)= alpha*sum_k A[m,k]*W[n,k]; atomic accumulate when gridDim.z>1
__global__ __launch_bounds__(512, 2) void gemm256_kernel(
    const __bf16* __restrict__ A, const __bf16* __restrict__ W,
    float* __restrict__ out, int N, int K, int ldo, float alpha)
{
  __shared__ __align__(16) __bf16 As[2][256 * 64];   // 32 KB each
  __shared__ __align__(16) __bf16 Bs[2][256 * 64];
  const int tid = threadIdx.x;
  const int lane = tid & 63, wave = tid >> 6;
  const int fr = lane & 15, fq = lane >> 4;

  // XCD swizzle over x*y (divisible by 8 for all launches)
  const int nwg = (int)(gridDim.x * gridDim.y);
  int lid = (int)(blockIdx.y * gridDim.x + blockIdx.x);
  lid = (lid & 7) * (nwg >> 3) + (lid >> 3);
  const int m0 = (lid & 7) * 256;          // gridDim.x == 8 always
  const int n0 = (lid >> 3) * 256;
  const int wm = (wave >> 2) * 128;        // 2 M-waves
  const int wn = (wave & 3) * 64;          // 4 N-waves

  const int KS = K / gridDim.z;
  const int kbase = (int)blockIdx.z * KS;

  // staging: issue q covers rows q*64 + wave*8 + (lane>>3), 16B per lane
  const int strow = wave * 8 + (lane >> 3);
  const int stcol = (lane & 7) * 8;
  const __bf16* gA = A + (size_t)(m0 + strow) * K + kbase + stcol;
  const __bf16* gB[4];
#pragma unroll
  for (int q = 0; q < 4; q++) {
    int nr = n0 + q * 64 + strow;
    if (nr >= N) nr = N - 1;
    gB[q] = W + (size_t)nr * K + kbase + stcol;
  }
  const int sdst = wave * 512;   // element offset of wave's 1 KB chunk per issue

  floatx4 acc[8][4];
#pragma unroll
  for (int i = 0; i < 8; i++)
#pragma unroll
    for (int j = 0; j < 4; j++) acc[i][j] = (floatx4){0.f, 0.f, 0.f, 0.f};

  // prologue: stage K-tile 0 into buf 0
#pragma unroll
  for (int q = 0; q < 4; q++) {
    async16(gA + (size_t)q * 64 * K, &As[0][q * 4096 + sdst]);
    async16(gB[q],                   &Bs[0][q * 4096 + sdst]);
  }
  __syncthreads();

  const int nsteps = KS >> 6;
  int cur = 0;
  for (int s = 0; s < nsteps; ++s) {
    if (s + 1 < nsteps) {
      const int ko = (s + 1) * 64;
#pragma unroll
      for (int q = 0; q < 4; q++) {
        async16(gA + ko + (size_t)q * 64 * K, &As[cur ^ 1][q * 4096 + sdst]);
        async16(gB[q] + ko,                   &Bs[cur ^ 1][q * 4096 + sdst]);
      }
    }

    // compute: B frags held, A frags streamed per row-frag
    bf16x8 bF[4][2];
#pragma unroll
    for (int j = 0; j < 4; j++)
#pragma unroll
      for (int t = 0; t < 2; t++)
        bF[j][t] = *(const bf16x8*)&Bs[cur][(wn + j * 16 + fr) * 64 + t * 32 + fq * 8];
#pragma unroll
    for (int i = 0; i < 8; i++) {
      bf16x8 a0 = *(const bf16x8*)&As[cur][(wm + i * 16 + fr) * 64 + fq * 8];
      bf16x8 a1 = *(const bf16x8*)&As[cur][(wm + i * 16 + fr) * 64 + 32 + fq * 8];
#pragma unroll
      for (int j = 0; j < 4; j++) {
        acc[i][j] = __builtin_amdgcn_mfma_f32_16x16x32_bf16(a0, bF[j][0], acc[i][j], 0, 0, 0);
        acc[i][j] = __builtin_amdgcn_mfma_f32_16x16x32_bf16(a1, bF[j][1], acc[i][j], 0, 0, 0);
      }
    }
    __syncthreads();
    cur ^= 1;
  }

  const bool at = (gridDim.z > 1);
#pragma unroll
  for (int i = 0; i < 8; i++) {
#pragma unroll
    for (int r = 0; r < 4; r++) {
      const int m = m0 + wm + i * 16 + fq * 4 + r;
      float* orow = out + (size_t)m * ldo;
#pragma unroll
      for (int j = 0; j < 4; j++) {
        const int n = n0 + wn + j * 16 + fr;
        if (n < N) {
          float vv = acc[i][j][r] * alpha;
          if (at) atomicAdd(&orow[n], vv);
          else    orow[n] = vv;
        }
      }
    }
  }
}

// ---------------- RMSNorm (bf16 out + optional fp32 out + residual copy) ----
__global__ __launch_bounds__(256) void rms_kernel(
    const float* __restrict__ in, const float* __restrict__ w,
    __bf16* __restrict__ outb, float* __restrict__ outf, float* __restrict__ copy)
{
  __shared__ float buf[HID];
  __shared__ float red[8];
  const int tid = threadIdx.x;
  const size_t t = blockIdx.x;
  const float* row = in + t * HID;
  float ss = 0.f;
  for (int i = tid; i < HID; i += 256) { float x = row[i]; buf[i] = x; ss += x * x; }
  float tot = block_sum(ss, red);
  float inv = rsqrtf(tot / (float)HID + 1e-5f);
  for (int i = tid; i < HID; i += 256) {
    float x = buf[i];
    float val = x * inv * w[i];
    outb[t * HID + i] = (__bf16)val;
    if (outf) outf[t * HID + i] = val;
    if (copy) copy[t * HID + i] = x;
  }
}

// ---------------- mup column-scale vector ----------------
__global__ void mup_kernel(float* __restrict__ mup) {
  int i = blockIdx.x * 256 + threadIdx.x;
  if (i >= INPROJ_N) return;
  float v = (i < DSSM) ? 1.0f
          : (i < 2 * DSSM) ? 0.9f
          : (i < 2 * DSSM + MS) ? 0.8f
          : (i < 2 * DSSM + 2 * MS) ? 1.1f
          : 1.2f;
  mup[i] = v;
}

// ---------------- RoPE + split qkv (bf16 out; 0.125 softmax scale folded into q)
__global__ __launch_bounds__(256) void rope_kernel(
    const float* __restrict__ qkv, const int* __restrict__ positions,
    __bf16* __restrict__ q, __bf16* __restrict__ k, __bf16* __restrict__ v)
{
  __shared__ float inv_s[32];
  const int tid = threadIdx.x;
  const size_t t = blockIdx.x;
  const int l = (int)(t & (L_ - 1));
  if (tid < 32) inv_s[tid] = powf(1.0e11f, -(float)(2 * tid) / 64.f);
  __syncthreads();
  const float pos = (float)positions[l];
  const float* src = qkv + t * QKV_N;
  for (int idx = tid; idx < 1536; idx += 256) {
    int head = idx >> 5, hd = idx & 31;
    if (head < 32) {
      float ang = pos * inv_s[hd];
      float c = cosf(ang), sn = sinf(ang);
      float x1 = src[head * 64 + hd], x2 = src[head * 64 + 32 + hd];
      __bf16* dst = q + (t * NH + head) * HD;
      dst[hd] = (__bf16)((x1 * c - x2 * sn) * 0.125f);
      dst[hd + 32] = (__bf16)((x2 * c + x1 * sn) * 0.125f);
    } else if (head < 40) {
      int kk = head - 32;
      float ang = pos * inv_s[hd];
      float c = cosf(ang), sn = sinf(ang);
      float x1 = src[2048 + kk * 64 + hd] * 0.7f;
      float x2 = src[2048 + kk * 64 + 32 + hd] * 0.7f;
      __bf16* dst = k + (t * NKV + kk) * HD;
      dst[hd] = (__bf16)(x1 * c - x2 * sn);
      dst[hd + 32] = (__bf16)(x2 * c + x1 * sn);
    } else {
      int vv = head - 40;
      __bf16* dst = v + (t * NKV + vv) * HD;
      dst[hd] = (__bf16)src[2560 + vv * 64 + hd];
      dst[hd + 32] = (__bf16)src[2560 + vv * 64 + 32 + hd];
    }
  }
}

// ---------------- flash attention, bf16 in/out, 64-query tile per block -----
__global__ __launch_bounds__(256) void fattn_kernel(
    const __bf16* __restrict__ q, const __bf16* __restrict__ k,
    const __bf16* __restrict__ v, __bf16* __restrict__ out)
{
  __shared__ __align__(16) __bf16 Vt[64][72];      // [dim][key]
  __shared__ __align__(16) __bf16 Ps[4][16][72];   // per-wave P strip [q16][key]
  const int tid = threadIdx.x;
  const int wave = tid >> 6, lane = tid & 63;
  const int fr = lane & 15, fq = lane >> 4;
  const int qt = (int)(gridDim.x - 1) - blockIdx.x;   // big tiles dispatch first
  const int h = blockIdx.y, b = blockIdx.z, g = h >> 2;
  const int l0 = qt * 64;

  bf16x8 qf[2];
  {
    const int qrow = l0 + wave * 16 + fr;
    const __bf16* qp = q + (((size_t)(b * L_ + qrow)) * NH + h) * HD;
    qf[0] = *(const bf16x8*)&qp[fq * 8];
    qf[1] = *(const bf16x8*)&qp[32 + fq * 8];
  }

  floatx4 O[4];
  float m_run[4], l_run[4];
#pragma unroll
  for (int i = 0; i < 4; i++) { O[i] = (floatx4){0.f,0.f,0.f,0.f}; m_run[i] = -3.0e38f; l_run[i] = 0.f; }

  for (int kt = 0; kt <= qt; kt++) {
    __syncthreads();
#pragma unroll
    for (int pp = 0; pp < 4; pp++) {
      const int kb = pp * 4 + wave;
      bf16x4 pk;
#pragma unroll
      for (int c = 0; c < 4; c++)
        pk[c] = v[(((size_t)(b * L_ + kt * 64 + kb * 4 + c)) * NKV + g) * HD + lane];
      *(bf16x4*)&Vt[lane][kb * 4] = pk;
    }

    floatx4 S[4];
#pragma unroll
    for (int j = 0; j < 4; j++) {
      const __bf16* kp = k + (((size_t)(b * L_ + kt * 64 + j * 16 + fr)) * NKV + g) * HD;
      floatx4 sa = (floatx4){0.f,0.f,0.f,0.f};
#pragma unroll
      for (int s = 0; s < 2; s++) {
        bf16x8 kf = *(const bf16x8*)&kp[s * 32 + fq * 8];
        sa = __builtin_amdgcn_mfma_f32_16x16x32_bf16(qf[s], kf, sa, 0, 0, 0);
      }
      S[j] = sa;
    }

    if (kt == qt) {
      const int qbase = wave * 16 + fq * 4;
#pragma unroll
      for (int j = 0; j < 4; j++)
#pragma unroll
        for (int r = 0; r < 4; r++)
          if (j * 16 + fr > qbase + r) S[j][r] = -1.0e30f;
    }

    float rm[4], alpha[4], rsum[4];
#pragma unroll
    for (int r = 0; r < 4; r++)
      rm[r] = fmaxf(fmaxf(S[0][r], S[1][r]), fmaxf(S[2][r], S[3][r]));
#pragma unroll
    for (int msk = 1; msk <= 8; msk <<= 1)
#pragma unroll
      for (int r = 0; r < 4; r++) rm[r] = fmaxf(rm[r], __shfl_xor(rm[r], msk, 64));
#pragma unroll
    for (int r = 0; r < 4; r++) {
      float mnew = fmaxf(m_run[r], rm[r]);
      alpha[r] = __expf(m_run[r] - mnew);
      m_run[r] = mnew;
    }
#pragma unroll
    for (int j = 0; j < 4; j++)
#pragma unroll
      for (int r = 0; r < 4; r++) S[j][r] = __expf(S[j][r] - m_run[r]);
#pragma unroll
    for (int r = 0; r < 4; r++)
      rsum[r] = S[0][r] + S[1][r] + S[2][r] + S[3][r];
#pragma unroll
    for (int msk = 1; msk <= 8; msk <<= 1)
#pragma unroll
      for (int r = 0; r < 4; r++) rsum[r] += __shfl_xor(rsum[r], msk, 64);
#pragma unroll
    for (int r = 0; r < 4; r++) l_run[r] = l_run[r] * alpha[r] + rsum[r];
#pragma unroll
    for (int d4 = 0; d4 < 4; d4++)
#pragma unroll
      for (int r = 0; r < 4; r++) O[d4][r] *= alpha[r];

#pragma unroll
    for (int j = 0; j < 4; j++)
#pragma unroll
      for (int r = 0; r < 4; r++)
        Ps[wave][fq * 4 + r][j * 16 + fr] = (__bf16)S[j][r];

    __syncthreads();

#pragma unroll
    for (int s = 0; s < 2; s++) {
      bf16x8 pf = *(const bf16x8*)&Ps[wave][fr][s * 32 + fq * 8];
#pragma unroll
      for (int d4 = 0; d4 < 4; d4++) {
        bf16x8 vf = *(const bf16x8*)&Vt[d4 * 16 + fr][s * 32 + fq * 8];
        O[d4] = __builtin_amdgcn_mfma_f32_16x16x32_bf16(pf, vf, O[d4], 0, 0, 0);
      }
    }
  }

  float rl[4];
#pragma unroll
  for (int r = 0; r < 4; r++) rl[r] = 1.f / l_run[r];
#pragma unroll
  for (int d4 = 0; d4 < 4; d4++)
#pragma unroll
    for (int r = 0; r < 4; r++) {
      const int qg = l0 + wave * 16 + fq * 4 + r;
      out[((size_t)(b * L_ + qg)) * HID + h * 64 + d4 * 16 + fr] = (__bf16)(O[d4][r] * rl[r]);
    }
}

// ---------------- exact-fp32 recompute of the 32 dt columns of in_proj ------
__global__ __launch_bounds__(256) void dtfix_kernel(
    const float* __restrict__ hs_ln, const float* __restrict__ w, float* __restrict__ proj)
{
  const size_t t = blockIdx.x;
  const int tid = threadIdx.x;
  const int o = tid >> 3, part = tid & 7;
  const float* a = hs_ln + t * HID;
  const float* wr = w + (size_t)(INPROJ_N - MH + o) * HID;
  float s = 0.f;
  for (int kk = part * 4; kk < HID; kk += 32) {
    const float4 av = *(const float4*)&a[kk];
    const float4 wv = *(const float4*)&wr[kk];
    s += av.x * wv.x + av.y * wv.y + av.z * wv.z + av.w * wv.w;
  }
  s += __shfl_xor(s, 1);
  s += __shfl_xor(s, 2);
  s += __shfl_xor(s, 4);
  if (part == 0) proj[t * INPROJ_N + (INPROJ_N - MH) + o] = s * 1.32f; // SSM_IN*mup_dt
}

// ---------------- depthwise causal conv (MK=4) + bias + silu ----------------
__global__ __launch_bounds__(256) void conv_kernel(
    const float* __restrict__ proj, const float* __restrict__ cw,
    const float* __restrict__ cb, float* __restrict__ xbc)
{
  const int c = blockIdx.x * 256 + threadIdx.x;
  if (c >= CONV_DIM) return;
  const int t = blockIdx.y;
  const int l = t & (L_ - 1);
  float acc = cb[c];
#pragma unroll
  for (int kk = 0; kk < MK; kk++) {
    int lp = l - (MK - 1) + kk;
    if (lp >= 0)
      acc += proj[((size_t)(t - (MK - 1) + kk)) * INPROJ_N + DSSM + c] * cw[c * MK + kk];
  }
  xbc[(size_t)t * CONV_DIM + c] = acc / (1.f + __expf(-acc));
}

// ---------------- chunked Mamba2 scan, stage A: intra-chunk (MFMA) ----------
__global__ __launch_bounds__(256) void scanA_kernel(
    const float* __restrict__ xbc, const float* __restrict__ proj,
    const float* __restrict__ A_log, const float* __restrict__ dt_bias,
    const float* __restrict__ Dp,
    float* __restrict__ y, float* __restrict__ Tbuf,
    float* __restrict__ lam, float* __restrict__ dec)
{
  __shared__ __align__(16) __bf16 xT[64][72];    // [p][l]
  __shared__ __align__(16) __bf16 BTw[64][72];   // [s][l] (scaled)
  __shared__ __align__(16) __bf16 Braw[64][72];  // [l][s]
  __shared__ __align__(16) __bf16 Craw[64][72];  // [l][s]
  __shared__ __align__(16) __bf16 Ps[4][16][72]; // per-wave M strip
  __shared__ float dt_s[64], cum_s[64];

  const int tid = threadIdx.x;
  const int lane = tid & 63, wave = tid >> 6;
  const int fr = lane & 15, fq = lane >> 4;
  const int c = blockIdx.x, h = blockIdx.y, b = blockIdx.z;
  const int t0 = b * L_ + c * CL;
  const float Ah = -expf(A_log[h]);
  const float dtb = dt_bias[h], Dh = Dp[h];

  if (wave == 0) {
    float draw = proj[(size_t)(t0 + lane) * INPROJ_N + (INPROJ_N - MH) + h];
    float dtv = draw + dtb;
    dtv = (dtv > 20.f) ? dtv : log1pf(__expf(dtv));
    float cs = dtv * Ah;
#pragma unroll
    for (int d = 1; d < 64; d <<= 1) {
      float nv = __shfl_up(cs, d, 64);
      if (lane >= d) cs += nv;
    }
    dt_s[lane] = dtv;
    cum_s[lane] = cs;
  }

#pragma unroll
  for (int pass = 0; pass < 4; pass++) {
    const int l = pass * 16 + (tid >> 4);
    const int s4 = (tid & 15) * 4;
    const float* rowp = xbc + (size_t)(t0 + l) * CONV_DIM;
    float4 xv = *(const float4*)&rowp[h * 64 + s4];
    float4 bv = *(const float4*)&rowp[DSSM + s4];
    float4 cv = *(const float4*)&rowp[DSSM + MS + s4];
    xT[s4 + 0][l] = (__bf16)xv.x;
    xT[s4 + 1][l] = (__bf16)xv.y;
    xT[s4 + 2][l] = (__bf16)xv.z;
    xT[s4 + 3][l] = (__bf16)xv.w;
    bf16x4 b4; b4[0]=(__bf16)bv.x; b4[1]=(__bf16)bv.y; b4[2]=(__bf16)bv.z; b4[3]=(__bf16)bv.w;
    *(bf16x4*)&Braw[l][s4] = b4;
    bf16x4 c4; c4[0]=(__bf16)cv.x; c4[1]=(__bf16)cv.y; c4[2]=(__bf16)cv.z; c4[3]=(__bf16)cv.w;
    *(bf16x4*)&Craw[l][s4] = c4;
  }
  __syncthreads();

  const float cend = cum_s[63];
#pragma unroll
  for (int pass = 0; pass < 4; pass++) {
    const int l = pass * 16 + (tid >> 4);
    const int s4 = (tid & 15) * 4;
    const float wl = __expf(cend - cum_s[l]) * dt_s[l];
    float4 bv = *(const float4*)&xbc[(size_t)(t0 + l) * CONV_DIM + DSSM + s4];
    BTw[s4 + 0][l] = (__bf16)(bv.x * wl);
    BTw[s4 + 1][l] = (__bf16)(bv.y * wl);
    BTw[s4 + 2][l] = (__bf16)(bv.z * wl);
    BTw[s4 + 3][l] = (__bf16)(bv.w * wl);
  }

  {
    bf16x8 aF0 = *(const bf16x8*)&Craw[wave * 16 + fr][fq * 8];
    bf16x8 aF1 = *(const bf16x8*)&Craw[wave * 16 + fr][fq * 8 + 32];
#pragma unroll
    for (int j = 0; j < 4; j++) {
      floatx4 s = (floatx4){0.f,0.f,0.f,0.f};
      bf16x8 b0 = *(const bf16x8*)&Braw[j * 16 + fr][fq * 8];
      bf16x8 b1 = *(const bf16x8*)&Braw[j * 16 + fr][fq * 8 + 32];
      s = __builtin_amdgcn_mfma_f32_16x16x32_bf16(aF0, b0, s, 0, 0, 0);
      s = __builtin_amdgcn_mfma_f32_16x16x32_bf16(aF1, b1, s, 0, 0, 0);
      const int m = j * 16 + fr;
      const float dtm = dt_s[m], cmm = cum_s[m];
#pragma unroll
      for (int r = 0; r < 4; r++) {
        const int lR = wave * 16 + fq * 4 + r;
        float f = (m <= lR) ? __expf(cum_s[lR] - cmm) * dtm : 0.f;
        Ps[wave][fq * 4 + r][m] = (__bf16)(s[r] * f);
      }
    }
  }
  __syncthreads();

  {
    bf16x8 aF0 = *(const bf16x8*)&Ps[wave][fr][fq * 8];
    bf16x8 aF1 = *(const bf16x8*)&Ps[wave][fr][fq * 8 + 32];
#pragma unroll
    for (int j = 0; j < 4; j++) {
      floatx4 s = (floatx4){0.f,0.f,0.f,0.f};
      bf16x8 b0 = *(const bf16x8*)&xT[j * 16 + fr][fq * 8];
      bf16x8 b1 = *(const bf16x8*)&xT[j * 16 + fr][fq * 8 + 32];
      s = __builtin_amdgcn_mfma_f32_16x16x32_bf16(aF0, b0, s, 0, 0, 0);
      s = __builtin_amdgcn_mfma_f32_16x16x32_bf16(aF1, b1, s, 0, 0, 0);
      const int p = j * 16 + fr;
#pragma unroll
      for (int r = 0; r < 4; r++) {
        const int lR = wave * 16 + fq * 4 + r;
        float xval = (float)xT[p][lR];
        y[(size_t)(t0 + lR) * DSSM + h * 64 + p] = s[r] + Dh * xval;
      }
    }
  }

  {
    float* Tb = Tbuf + ((size_t)((b * MH + h) * CH + c)) * 4096;
    bf16x8 aF0 = *(const bf16x8*)&xT[wave * 16 + fr][fq * 8];
    bf16x8 aF1 = *(const bf16x8*)&xT[wave * 16 + fr][fq * 8 + 32];
#pragma unroll
    for (int j = 0; j < 4; j++) {
      floatx4 s = (floatx4){0.f,0.f,0.f,0.f};
      bf16x8 b0 = *(const bf16x8*)&BTw[j * 16 + fr][fq * 8];
      bf16x8 b1 = *(const bf16x8*)&BTw[j * 16 + fr][fq * 8 + 32];
      s = __builtin_amdgcn_mfma_f32_16x16x32_bf16(aF0, b0, s, 0, 0, 0);
      s = __builtin_amdgcn_mfma_f32_16x16x32_bf16(aF1, b1, s, 0, 0, 0);
#pragma unroll
      for (int r = 0; r < 4; r++)
        Tb[(wave * 16 + fq * 4 + r) * 64 + j * 16 + fr] = s[r];
    }
  }

  if (tid == 0) lam[(b * MH + h) * CH + c] = __expf(cend);
  if (tid >= 64 && tid < 128)
    dec[((size_t)((b * MH + h) * CH + c)) * 64 + (tid - 64)] = __expf(cum_s[tid - 64]);
}

// ---------------- chunked scan, stage B: inter-chunk state scan -------------
__global__ __launch_bounds__(256) void scanB_kernel(
    const float* __restrict__ xbc, const float* __restrict__ Tbuf,
    const float* __restrict__ lam, const float* __restrict__ dec,
    float* __restrict__ y)
{
  __shared__ __align__(16) float S[64][68];
  __shared__ __align__(16) __bf16 Cc[64][72];
  __shared__ float decl[64];
  const int tid = threadIdx.x;
  const int lane = tid & 63, wave = tid >> 6;
  const int fr = lane & 15, fq = lane >> 4;
  const int h = blockIdx.x, b = blockIdx.y;

  const int sown = tid & 63, pbase = (tid >> 6) * 16;
#pragma unroll
  for (int i = 0; i < 16; i++) S[pbase + i][sown] = 0.f;
  __syncthreads();

  for (int c = 0; c < CH; c++) {
    const int t0 = b * L_ + c * CL;
#pragma unroll
    for (int pass = 0; pass < 4; pass++) {
      const int l = pass * 16 + (tid >> 4);
      const int s4 = (tid & 15) * 4;
      float4 cv = *(const float4*)&xbc[(size_t)(t0 + l) * CONV_DIM + DSSM + MS + s4];
      bf16x4 c4; c4[0]=(__bf16)cv.x; c4[1]=(__bf16)cv.y; c4[2]=(__bf16)cv.z; c4[3]=(__bf16)cv.w;
      *(bf16x4*)&Cc[l][s4] = c4;
    }
    if (tid < 64) decl[tid] = dec[((size_t)((b * MH + h) * CH + c)) * 64 + tid];
    __syncthreads();

    if (c > 0) {
      bf16x8 aF0 = *(const bf16x8*)&Cc[wave * 16 + fr][fq * 8];
      bf16x8 aF1 = *(const bf16x8*)&Cc[wave * 16 + fr][fq * 8 + 32];
#pragma unroll
      for (int j = 0; j < 4; j++) {
        const float* srow = &S[j * 16 + fr][0];
        float4 s0 = *(const float4*)&srow[fq * 8];
        float4 s1 = *(const float4*)&srow[fq * 8 + 4];
        float4 s2 = *(const float4*)&srow[fq * 8 + 32];
        float4 s3 = *(const float4*)&srow[fq * 8 + 36];
        bf16x8 b0 = pack8(s0, s1, 1.f);
        bf16x8 b1 = pack8(s2, s3, 1.f);
        floatx4 acc = (floatx4){0.f,0.f,0.f,0.f};
        acc = __builtin_amdgcn_mfma_f32_16x16x32_bf16(aF0, b0, acc, 0, 0, 0);
        acc = __builtin_amdgcn_mfma_f32_16x16x32_bf16(aF1, b1, acc, 0, 0, 0);
        const int p = j * 16 + fr;
#pragma unroll
        for (int r = 0; r < 4; r++) {
          const int lR = wave * 16 + fq * 4 + r;
          float* yp = &y[(size_t)(t0 + lR) * DSSM + h * 64 + p];
          *yp += decl[lR] * acc[r];
        }
      }
    }
    __syncthreads();

    const float lc = lam[(b * MH + h) * CH + c];
    const float* Tb = Tbuf + ((size_t)((b * MH + h) * CH + c)) * 4096;
#pragma unroll
    for (int i = 0; i < 16; i++) {
      float tv = Tb[(pbase + i) * 64 + sown];
      S[pbase + i][sown] = lc * S[pbase + i][sown] + tv;
    }
    __syncthreads();
  }
}

// ---------------- gating (y * silu(z)) + RMSNorm -> bf16 ----------------
__global__ __launch_bounds__(256) void gating_kernel(
    const float* __restrict__ y, const float* __restrict__ proj,
    const float* __restrict__ nw, __bf16* __restrict__ g)
{
  __shared__ float buf[DSSM];
  __shared__ float red[8];
  const int tid = threadIdx.x;
  const size_t t = blockIdx.x;
  float ss = 0.f;
  for (int i = tid; i < DSSM; i += 256) {
    float zv = proj[t * INPROJ_N + i];
    float yv = y[t * DSSM + i];
    float gv = yv * zv / (1.f + __expf(-zv));
    buf[i] = gv;
    ss += gv * gv;
  }
  float tot = block_sum(ss, red);
  float inv = rsqrtf(tot / (float)DSSM + 1e-5f);
  for (int i = tid; i < DSSM; i += 256) g[t * DSSM + i] = (__bf16)(buf[i] * inv * nw[i]);
}

// ---------------- SwiGLU activation -> bf16 (x4 vectorized) ----------------
__global__ __launch_bounds__(256) void act_kernel(
    const float* __restrict__ gu, __bf16* __restrict__ act)
{
  const int i = (blockIdx.x * 256 + threadIdx.x) * 4;
  const size_t t = blockIdx.y;
  float4 g4 = *(const float4*)&gu[t * (2 * INTER) + i];
  float4 u4 = *(const float4*)&gu[t * (2 * INTER) + INTER + i];
  bf16x4 o;
  float gt;
  gt = g4.x * 0.9f; o[0] = (__bf16)(gt / (1.f + __expf(-gt)) * u4.x);
  gt = g4.y * 0.9f; o[1] = (__bf16)(gt / (1.f + __expf(-gt)) * u4.y);
  gt = g4.z * 0.9f; o[2] = (__bf16)(gt / (1.f + __expf(-gt)) * u4.z);
  gt = g4.w * 0.9f; o[3] = (__bf16)(gt / (1.f + __expf(-gt)) * u4.w);
  *(bf16x4*)&act[t * INTER + i] = o;
}

// ---------------- launcher ----------------
extern "C" void kernel_launch(void* const* d_in, const int* in_sizes, int n_in,
                              void* d_out, int out_size, void* d_ws, size_t ws_size,
                              hipStream_t stream)
{
  const float* hidden      = (const float*)d_in[0];
  const int*   positions   = (const int*)d_in[1];
  const float* w_in_ln     = (const float*)d_in[2];
  const float* qkv_w       = (const float*)d_in[3];
  const float* o_w         = (const float*)d_in[4];
  const float* in_proj_w   = (const float*)d_in[5];
  const float* conv_w      = (const float*)d_in[6];
  const float* conv_b      = (const float*)d_in[7];
  const float* A_log       = (const float*)d_in[8];
  const float* dt_bias     = (const float*)d_in[9];
  const float* Dp          = (const float*)d_in[10];
  const float* ssm_norm_w  = (const float*)d_in[11];
  const float* out_proj_w  = (const float*)d_in[12];
  const float* w_pre_ff_ln = (const float*)d_in[13];
  const float* gate_up_w   = (const float*)d_in[14];
  const float* down_w      = (const float*)d_in[15];
  (void)in_sizes; (void)n_in; (void)out_size; (void)ws_size;

  float* ws   = (float*)d_ws;
  float* outp = (float*)d_out;

  float*  h2    = ws + OFF_H2;
  float*  mup   = ws + OFF_MUP;
  __bf16* wqkv  = (__bf16*)(ws + OFF_WQKV);
  __bf16* win   = (__bf16*)(ws + OFF_WIN);
  __bf16* wo    = (__bf16*)(ws + OFF_WO);
  __bf16* wop   = (__bf16*)(ws + OFF_WOP);
  __bf16* hsb   = (__bf16*)(ws + OFF_HSB);
  float*  hsf   = ws + OFF_HSF;
  float*  qkv   = ws + OFF_QKV;
  __bf16* qb    = (__bf16*)(ws + OFF_Q);
  __bf16* kb    = (__bf16*)(ws + OFF_K);
  __bf16* vb    = (__bf16*)(ws + OFF_V);
  __bf16* attb  = (__bf16*)(ws + OFF_ATT);
  float*  proj  = ws + OFF_PROJ;
  float*  xbc   = ws + OFF_XBC;
  float*  y     = ws + OFF_Y;
  __bf16* gb    = (__bf16*)(ws + OFF_G);
  float*  Tbuf  = ws + OFF_TB;
  float*  dec   = ws + OFF_DEC;
  float*  lam   = ws + OFF_LAM;
  __bf16* hs2b  = (__bf16*)(ws + OFF_HS2B);
  float*  gu    = ws + OFF_GU;
  __bf16* actb  = (__bf16*)(ws + OFF_ACTB);
  __bf16* wb2   = (__bf16*)(ws + OFF_WB2);

  // phase-1 weight conversions (fp32 -> bf16)
  cvt_kernel<<<2048, 256, 0, stream>>>(qkv_w, wqkv, 786432);
  cvt_kernel<<<2048, 256, 0, stream>>>(in_proj_w, win, 1089536);
  cvt_kernel<<<2048, 256, 0, stream>>>(o_w, wo, 524288);
  cvt_kernel<<<2048, 256, 0, stream>>>(out_proj_w, wop, 524288);
  mup_kernel<<<17, 256, 0, stream>>>(mup);
  rms_kernel<<<T_, 256, 0, stream>>>(hidden, w_in_ln, hsb, hsf, h2);

  // attention branch
  gemm_bf_kernel<<<dim3(16, 24, 1), 256, 0, stream>>>(hsb, wqkv, qkv, nullptr,
                                                      QKV_N, HID, QKV_N, 1.2f);
  rope_kernel<<<T_, 256, 0, stream>>>(qkv, positions, qb, kb, vb);
  fattn_kernel<<<dim3(L_ / 64, NH, B_), 256, 0, stream>>>(qb, kb, vb, attb);
  gemm256_kernel<<<dim3(8, 8, 4), 512, 0, stream>>>(attb, wo, h2,
                                                    HID, HID, HID, 0.8f);   // atomic += into residual

  // mamba branch
  gemm_bf_kernel<<<dim3(16, 34, 1), 256, 0, stream>>>(hsb, win, proj, mup,
                                                      INPROJ_N, HID, INPROJ_N, 1.1f);
  dtfix_kernel<<<T_, 256, 0, stream>>>(hsf, in_proj_w, proj);
  conv_kernel<<<dim3(9, T_), 256, 0, stream>>>(proj, conv_w, conv_b, xbc);
  scanA_kernel<<<dim3(CH, MH, B_), 256, 0, stream>>>(xbc, proj, A_log, dt_bias, Dp,
                                                     y, Tbuf, lam, dec);
  scanB_kernel<<<dim3(MH, B_), 256, 0, stream>>>(xbc, Tbuf, lam, dec, y);
  gating_kernel<<<T_, 256, 0, stream>>>(y, proj, ssm_norm_w, gb);
  gemm256_kernel<<<dim3(8, 8, 4), 512, 0, stream>>>(gb, wop, h2,
                                                    HID, HID, HID, 0.9f);   // atomic += into residual

  // MLP (wb2 time-shared: gate half -> up half -> down_w)
  rms_kernel<<<T_, 256, 0, stream>>>(h2, w_pre_ff_ln, hs2b, nullptr, nullptr);
  cvt_kernel<<<2048, 256, 0, stream>>>(gate_up_w, wb2, 2097152);
  gemm256_kernel<<<dim3(8, 32, 1), 512, 0, stream>>>(hs2b, wb2, gu,
                                                     INTER, HID, 2 * INTER, 1.0f);
  cvt_kernel<<<2048, 256, 0, stream>>>(gate_up_w + (size_t)INTER * HID, wb2, 2097152);
  gemm256_kernel<<<dim3(8, 32, 1), 512, 0, stream>>>(hs2b, wb2, gu + INTER,
                                                     INTER, HID, 2 * INTER, 1.0f);
  act_kernel<<<dim3(INTER / 1024, T_), 256, 0, stream>>>(gu, actb);
  cvt_kernel<<<2048, 256, 0, stream>>>(down_w, wb2, 2097152);
  copy_kernel<<<4096, 256, 0, stream>>>(h2, outp);
  gemm256_kernel<<<dim3(8, 8, 4), 512, 0, stream>>>(actb, wb2, outp,
                                                    HID, INTER, HID, 0.8f); // atomic += onto residual copy
}

// Round 4
// 1165.614 us; speedup vs baseline: 1.4347x; 1.0218x over previous
//
#include <hip/hip_runtime.h>
#include <hip/hip_bf16.h>
#include <math.h>

// ---------------- problem constants ----------------
#define B_      2
#define L_      1024
#define HID     2048
#define T_      (B_*L_)      // 2048 tokens
#define NH      32
#define HD      64
#define NKV     8
#define INTER   8192
#define DSSM    2048
#define MH      32
#define MP      64
#define MS      64
#define MK      4
#define CONV_DIM 2176
#define QKV_N   3072
#define INPROJ_N 4256
#define CH      16     // scan chunks
#define CL      64     // chunk length

typedef __bf16 bf16x8 __attribute__((ext_vector_type(8)));
typedef __bf16 bf16x4 __attribute__((ext_vector_type(4)));
typedef float  floatx4 __attribute__((ext_vector_type(4)));

// ---------------- workspace layout (float elements) ----------------
// persistent
static const size_t OFF_H2   = 0;                       // 4,194,304 residual stream (fp32)
static const size_t OFF_MUP  = 4194304;                 // 16,384 slot
static const size_t AR       = 4210688;                 // arena base
// phase 1
static const size_t OFF_WQKV = AR;                      // bf16 6,291,456 el = 3,145,728 fl
static const size_t OFF_WIN  = OFF_WQKV + 3145728;      // bf16 8,716,288 el = 4,358,144 fl
static const size_t OFF_WO   = OFF_WIN  + 4358144;      // bf16 4,194,304 el = 2,097,152 fl
static const size_t OFF_WOP  = OFF_WO   + 2097152;      // bf16 4,194,304 el = 2,097,152 fl
static const size_t OFF_HSB  = OFF_WOP  + 2097152;      // bf16 hs_ln
static const size_t OFF_HSF  = OFF_HSB  + 2097152;      // fp32 hs_ln (dtfix)
static const size_t OFF_QKV  = OFF_HSF  + 4194304;      // fp32 6,291,456
static const size_t OFF_Q    = OFF_QKV  + 6291456;      // bf16 4,194,304 el
static const size_t OFF_K    = OFF_Q    + 2097152;      // bf16 1,048,576 el
static const size_t OFF_V    = OFF_K    + 524288;       // bf16 1,048,576 el
static const size_t OFF_ATT  = OFF_V    + 524288;       // bf16 4,194,304 el
static const size_t OFF_PROJ = OFF_ATT  + 2097152;      // fp32 8,716,288
static const size_t OFF_XBC  = OFF_PROJ + 8716288;      // fp32 4,456,448
static const size_t OFF_Y    = OFF_XBC  + 4456448;      // fp32 4,194,304
static const size_t OFF_G    = OFF_Y    + 4194304;      // bf16 4,194,304 el
// scan scratch aliases (qkv/q/v dead by scan time)
static const size_t OFF_TB   = OFF_QKV;                 // fp32 4,194,304 (Tbuf)
static const size_t OFF_DEC  = OFF_Q;                   // fp32 65,536
static const size_t OFF_LAM  = OFF_V;                   // fp32 1,024
// phase 2 (aliases phase-1 arena; everything above dead by MLP)
static const size_t OFF_HS2B = AR;                      // bf16 4,194,304 el
static const size_t OFF_GU   = AR + 2097152;            // fp32 33,554,432
static const size_t OFF_ACTB = OFF_GU + 33554432;       // bf16 16,777,216 el
static const size_t OFF_WB2  = OFF_ACTB + 8388608;      // bf16 16,777,216 el (gate/up/down_w time-shared)
// total = AR + 52,428,800 = 56,639,488 floats = 226.6 MB

// ---------------- helpers ----------------
__device__ inline float block_sum(float v, float* red) {
#pragma unroll
  for (int o = 32; o > 0; o >>= 1) v += __shfl_down(v, o, 64);
  const int lane = threadIdx.x & 63, wv = threadIdx.x >> 6;
  if (lane == 0) red[wv] = v;
  __syncthreads();
  if (threadIdx.x == 0) red[0] = red[0] + red[1] + red[2] + red[3];
  __syncthreads();
  float r = red[0];
  __syncthreads();
  return r;
}

__device__ inline bf16x8 pack8(float4 a, float4 b, float scale) {
  bf16x8 v;
  v[0] = (__bf16)(a.x * scale); v[1] = (__bf16)(a.y * scale);
  v[2] = (__bf16)(a.z * scale); v[3] = (__bf16)(a.w * scale);
  v[4] = (__bf16)(b.x * scale); v[5] = (__bf16)(b.y * scale);
  v[6] = (__bf16)(b.z * scale); v[7] = (__bf16)(b.w * scale);
  return v;
}

// async global->LDS 16B per lane (dest = wave-uniform base + lane*16)
__device__ __forceinline__ void async16(const void* g, void* l) {
  __builtin_amdgcn_global_load_lds(
      (const __attribute__((address_space(1))) void*)g,
      (__attribute__((address_space(3))) void*)l, 16, 0, 0);
}

// ---------------- fp32 -> bf16 conversion (grid-stride, x8) ----------------
__global__ __launch_bounds__(256) void cvt_kernel(
    const float* __restrict__ in, __bf16* __restrict__ outp, int n8)
{
  int i = blockIdx.x * 256 + threadIdx.x;
  const int stride = gridDim.x * 256;
  for (; i < n8; i += stride) {
    const float4* p = (const float4*)(in + (size_t)i * 8);
    float4 a = p[0], b = p[1];
    bf16x8 v;
    v[0] = (__bf16)a.x; v[1] = (__bf16)a.y; v[2] = (__bf16)a.z; v[3] = (__bf16)a.w;
    v[4] = (__bf16)b.x; v[5] = (__bf16)b.y; v[6] = (__bf16)b.z; v[7] = (__bf16)b.w;
    *(bf16x8*)(outp + (size_t)i * 8) = v;
  }
}

// ---------------- fp32 copy (outp <- h2 init for atomic down-GEMM) ----------
__global__ __launch_bounds__(256) void copy_kernel(
    const float* __restrict__ in, float* __restrict__ outp)
{
  const size_t i = ((size_t)blockIdx.x * 256 + threadIdx.x) * 4;
  *(float4*)&outp[i] = *(const float4*)&in[i];
}

// ---------------- GEMM 128x128 (bf16, dbuf global_load_lds) — qkv / in_proj -
// out[m,n] (+)= alpha*colscale[n]*sum_k A[m,k]*W[n,k]; atomic when gridDim.z>1
// gridDim.x == 16 (M tiles); nwg (x*y) divisible by 8.
__global__ __launch_bounds__(256) void gemm_bf_kernel(
    const __bf16* __restrict__ A, const __bf16* __restrict__ W,
    float* __restrict__ out, const float* __restrict__ colscale,
    int N, int K, int ldo, float alpha)
{
  __shared__ __align__(16) __bf16 As[2][128 * 32];
  __shared__ __align__(16) __bf16 Bs[2][128 * 32];
  const int tid = threadIdx.x;
  const int lane = tid & 63, wave = tid >> 6;
  const int fr = lane & 15, fq = lane >> 4;

  const int nwg = (int)(gridDim.x * gridDim.y);
  int lid = (int)(blockIdx.y * gridDim.x + blockIdx.x);
  lid = (lid & 7) * (nwg >> 3) + (lid >> 3);
  const int m0 = (lid & 15) * 128;
  const int n0 = (lid >> 4) * 128;
  const int wm = (wave >> 1) * 64, wn = (wave & 1) * 64;

  const int KS = K / gridDim.z;
  const int kbase = (int)blockIdx.z * KS;

  const int srow = wave * 32 + (lane >> 2);
  const int selem = (lane & 3) * 8;
  const __bf16* ga0 = A + (size_t)(m0 + srow) * K + kbase + selem;
  const __bf16* ga1 = ga0 + (size_t)16 * K;
  int wr0 = n0 + srow;      if (wr0 >= N) wr0 = N - 1;
  int wr1 = n0 + srow + 16; if (wr1 >= N) wr1 = N - 1;
  const __bf16* gb0 = W + (size_t)wr0 * K + kbase + selem;
  const __bf16* gb1 = W + (size_t)wr1 * K + kbase + selem;
  const int sbase = wave * 2 * 512;

  floatx4 acc[4][4];
#pragma unroll
  for (int i = 0; i < 4; i++)
#pragma unroll
    for (int j = 0; j < 4; j++) acc[i][j] = (floatx4){0.f, 0.f, 0.f, 0.f};

  async16(ga0, &As[0][sbase]); async16(ga1, &As[0][sbase + 512]);
  async16(gb0, &Bs[0][sbase]); async16(gb1, &Bs[0][sbase + 512]);
  ga0 += 32; ga1 += 32; gb0 += 32; gb1 += 32;
  __syncthreads();

  const int nsteps = KS >> 5;
  int cur = 0;
  for (int s = 0; s < nsteps; ++s) {
    if (s + 1 < nsteps) {
      async16(ga0, &As[cur ^ 1][sbase]); async16(ga1, &As[cur ^ 1][sbase + 512]);
      async16(gb0, &Bs[cur ^ 1][sbase]); async16(gb1, &Bs[cur ^ 1][sbase + 512]);
      ga0 += 32; ga1 += 32; gb0 += 32; gb1 += 32;
    }
    bf16x8 aF[4], bF[4];
#pragma unroll
    for (int i = 0; i < 4; i++)
      aF[i] = *(const bf16x8*)&As[cur][(wm + i * 16 + fr) * 32 + fq * 8];
#pragma unroll
    for (int j = 0; j < 4; j++)
      bF[j] = *(const bf16x8*)&Bs[cur][(wn + j * 16 + fr) * 32 + fq * 8];
#pragma unroll
    for (int i = 0; i < 4; i++)
#pragma unroll
      for (int j = 0; j < 4; j++)
        acc[i][j] = __builtin_amdgcn_mfma_f32_16x16x32_bf16(aF[i], bF[j], acc[i][j], 0, 0, 0);
    __syncthreads();
    cur ^= 1;
  }

  const bool at = (gridDim.z > 1);
#pragma unroll
  for (int i = 0; i < 4; i++) {
#pragma unroll
    for (int r = 0; r < 4; r++) {
      const int m = m0 + wm + i * 16 + fq * 4 + r;
      float* orow = out + (size_t)m * ldo;
#pragma unroll
      for (int j = 0; j < 4; j++) {
        const int n = n0 + wn + j * 16 + fr;
        if (n < N) {
          float vv = acc[i][j][r] * alpha;
          if (colscale) vv *= colscale[n];
          if (at) atomicAdd(&orow[n], vv);
          else    orow[n] = vv;
        }
      }
    }
  }
}

// ---------------- GEMM 256x256 pipelined (bf16, BK=64, counted vmcnt, T2 swz)
// grid (8, Ntiles, z); 512 threads; 128 KiB LDS; N,M multiples of 256.
// out[m,n] (+)= alpha*sum_k A[m,k]*W[n,k]; atomic accumulate when gridDim.z>1
// LDS layout: [buf][256 rows][64 cols] bf16, rows 128B. T2 swizzle: 16B-slot
// index XORed with (row&7); staged via pre-permuted per-lane GLOBAL source
// (rule 21: linear gload_lds dest + inverse-swz source + swz on read).
__global__ __launch_bounds__(512, 2) void gemm256p_kernel(
    const __bf16* __restrict__ A, const __bf16* __restrict__ W,
    float* __restrict__ out, int N, int K, int ldo, float alpha)
{
  __shared__ __align__(16) __bf16 As[2][256 * 64];   // 32 KB per buf
  __shared__ __align__(16) __bf16 Bs[2][256 * 64];
  const int tid = threadIdx.x;
  const int lane = tid & 63, wave = tid >> 6;
  const int fr = lane & 15, fq = lane >> 4;

  const int nwg = (int)(gridDim.x * gridDim.y);
  int lid = (int)(blockIdx.y * gridDim.x + blockIdx.x);
  lid = (lid & 7) * (nwg >> 3) + (lid >> 3);
  const int m0 = (lid & 7) * 256;          // gridDim.x == 8 always
  const int n0 = (lid >> 3) * 256;
  const int wmL = (wave >> 2) * 128;       // 2 M-waves
  const int wnL = (wave & 3) * 64;         // 4 N-waves

  const int KS = K / gridDim.z;
  const int kbase = (int)blockIdx.z * KS;

  // ---- staging geometry: 8 issues/K-tile (4 A + 4 B), 8 KB each ----
  // issue q covers rows q*64 + wave*8 + (lane>>3); lane's 16B within the row
  // goes to linear slot (lane&7); source slot pre-XORed so that the read-side
  // XOR (slot ^= row&7) recovers linear data.  row&7 == (lane>>3)&7 here.
  const int rwl = wave * 8 + (lane >> 3);
  const int csw = (((lane & 7) ^ ((lane >> 3) & 7))) * 8;   // element offset
  const __bf16* gAq[4];
  const __bf16* gBq[4];
#pragma unroll
  for (int q = 0; q < 4; q++) {
    gAq[q] = A + (size_t)(m0 + q * 64 + rwl) * K + kbase + csw;
    gBq[q] = W + (size_t)(n0 + q * 64 + rwl) * K + kbase + csw;
  }
  const int sdst = wave * 512;   // element offset of wave's 1 KB chunk per issue

#define STAGE256(buf, ko)                                        \
  do {                                                           \
    _Pragma("unroll")                                            \
    for (int q = 0; q < 4; q++) {                                \
      async16(gAq[q] + (ko), &As[buf][q * 4096 + sdst]);         \
      async16(gBq[q] + (ko), &Bs[buf][q * 4096 + sdst]);         \
    }                                                            \
  } while (0)

  floatx4 acc[8][4];
#pragma unroll
  for (int i = 0; i < 8; i++)
#pragma unroll
    for (int j = 0; j < 4; j++) acc[i][j] = (floatx4){0.f, 0.f, 0.f, 0.f};

  // prologue: stage K-tile 0 into buf 0
  STAGE256(0, 0);

  const int ns = KS >> 6;
  for (int kt = 0; kt < ns; ++kt) {
    const int c = kt & 1;
    if (kt + 1 < ns) {
      STAGE256(c ^ 1, (kt + 1) * 64);
      // kt's 8 loads are the oldest; keep kt+1's 8 in flight
      asm volatile("s_waitcnt vmcnt(8)" ::: "memory");
    } else {
      asm volatile("s_waitcnt vmcnt(0)" ::: "memory");
    }
    __builtin_amdgcn_s_barrier();     // all waves: tile kt fully in LDS

#pragma unroll
    for (int kh = 0; kh < 2; ++kh) {
      const int sw = ((kh * 4 + fq) ^ (fr & 7)) * 8;   // swizzled 16B slot
      bf16x8 aF[8], bF[4];
#pragma unroll
      for (int j = 0; j < 4; j++)
        bF[j] = *(const bf16x8*)&Bs[c][(wnL + j * 16 + fr) * 64 + sw];
#pragma unroll
      for (int i = 0; i < 8; i++)
        aF[i] = *(const bf16x8*)&As[c][(wmL + i * 16 + fr) * 64 + sw];
      asm volatile("s_waitcnt lgkmcnt(0)" ::: "memory");
      __builtin_amdgcn_sched_barrier(0);
      __builtin_amdgcn_s_setprio(1);
#pragma unroll
      for (int i = 0; i < 8; i++)
#pragma unroll
        for (int j = 0; j < 4; j++)
          acc[i][j] = __builtin_amdgcn_mfma_f32_16x16x32_bf16(aF[i], bF[j], acc[i][j], 0, 0, 0);
      __builtin_amdgcn_s_setprio(0);
    }
    __builtin_amdgcn_s_barrier();     // reads of buf c done before it is restaged
  }
#undef STAGE256

  const bool at = (gridDim.z > 1);
#pragma unroll
  for (int i = 0; i < 8; i++) {
#pragma unroll
    for (int r = 0; r < 4; r++) {
      const int m = m0 + wmL + i * 16 + fq * 4 + r;
      float* orow = out + (size_t)m * ldo;
#pragma unroll
      for (int j = 0; j < 4; j++) {
        const int n = n0 + wnL + j * 16 + fr;
        float vv = acc[i][j][r] * alpha;
        if (at) atomicAdd(&orow[n], vv);
        else    orow[n] = vv;
      }
    }
  }
}

// ---------------- RMSNorm (bf16 out + optional fp32 out + residual copy) ----
__global__ __launch_bounds__(256) void rms_kernel(
    const float* __restrict__ in, const float* __restrict__ w,
    __bf16* __restrict__ outb, float* __restrict__ outf, float* __restrict__ copy)
{
  __shared__ float buf[HID];
  __shared__ float red[8];
  const int tid = threadIdx.x;
  const size_t t = blockIdx.x;
  const float* row = in + t * HID;
  float ss = 0.f;
  for (int i = tid; i < HID; i += 256) { float x = row[i]; buf[i] = x; ss += x * x; }
  float tot = block_sum(ss, red);
  float inv = rsqrtf(tot / (float)HID + 1e-5f);
  for (int i = tid; i < HID; i += 256) {
    float x = buf[i];
    float val = x * inv * w[i];
    outb[t * HID + i] = (__bf16)val;
    if (outf) outf[t * HID + i] = val;
    if (copy) copy[t * HID + i] = x;
  }
}

// ---------------- mup column-scale vector ----------------
__global__ void mup_kernel(float* __restrict__ mup) {
  int i = blockIdx.x * 256 + threadIdx.x;
  if (i >= INPROJ_N) return;
  float v = (i < DSSM) ? 1.0f
          : (i < 2 * DSSM) ? 0.9f
          : (i < 2 * DSSM + MS) ? 0.8f
          : (i < 2 * DSSM + 2 * MS) ? 1.1f
          : 1.2f;
  mup[i] = v;
}

// ---------------- RoPE + split qkv (bf16 out; 0.125 softmax scale folded into q)
__global__ __launch_bounds__(256) void rope_kernel(
    const float* __restrict__ qkv, const int* __restrict__ positions,
    __bf16* __restrict__ q, __bf16* __restrict__ k, __bf16* __restrict__ v)
{
  __shared__ float inv_s[32];
  const int tid = threadIdx.x;
  const size_t t = blockIdx.x;
  const int l = (int)(t & (L_ - 1));
  if (tid < 32) inv_s[tid] = powf(1.0e11f, -(float)(2 * tid) / 64.f);
  __syncthreads();
  const float pos = (float)positions[l];
  const float* src = qkv + t * QKV_N;
  for (int idx = tid; idx < 1536; idx += 256) {
    int head = idx >> 5, hd = idx & 31;
    if (head < 32) {
      float ang = pos * inv_s[hd];
      float c = cosf(ang), sn = sinf(ang);
      float x1 = src[head * 64 + hd], x2 = src[head * 64 + 32 + hd];
      __bf16* dst = q + (t * NH + head) * HD;
      dst[hd] = (__bf16)((x1 * c - x2 * sn) * 0.125f);
      dst[hd + 32] = (__bf16)((x2 * c + x1 * sn) * 0.125f);
    } else if (head < 40) {
      int kk = head - 32;
      float ang = pos * inv_s[hd];
      float c = cosf(ang), sn = sinf(ang);
      float x1 = src[2048 + kk * 64 + hd] * 0.7f;
      float x2 = src[2048 + kk * 64 + 32 + hd] * 0.7f;
      __bf16* dst = k + (t * NKV + kk) * HD;
      dst[hd] = (__bf16)(x1 * c - x2 * sn);
      dst[hd + 32] = (__bf16)(x2 * c + x1 * sn);
    } else {
      int vv = head - 40;
      __bf16* dst = v + (t * NKV + vv) * HD;
      dst[hd] = (__bf16)src[2560 + vv * 64 + hd];
      dst[hd + 32] = (__bf16)src[2560 + vv * 64 + 32 + hd];
    }
  }
}

// ---------------- flash attention, bf16 in/out, 64-query tile per block -----
__global__ __launch_bounds__(256) void fattn_kernel(
    const __bf16* __restrict__ q, const __bf16* __restrict__ k,
    const __bf16* __restrict__ v, __bf16* __restrict__ out)
{
  __shared__ __align__(16) __bf16 Vt[64][72];      // [dim][key]
  __shared__ __align__(16) __bf16 Ps[4][16][72];   // per-wave P strip [q16][key]
  const int tid = threadIdx.x;
  const int wave = tid >> 6, lane = tid & 63;
  const int fr = lane & 15, fq = lane >> 4;
  const int qt = (int)(gridDim.x - 1) - blockIdx.x;   // big tiles dispatch first
  const int h = blockIdx.y, b = blockIdx.z, g = h >> 2;
  const int l0 = qt * 64;

  bf16x8 qf[2];
  {
    const int qrow = l0 + wave * 16 + fr;
    const __bf16* qp = q + (((size_t)(b * L_ + qrow)) * NH + h) * HD;
    qf[0] = *(const bf16x8*)&qp[fq * 8];
    qf[1] = *(const bf16x8*)&qp[32 + fq * 8];
  }

  floatx4 O[4];
  float m_run[4], l_run[4];
#pragma unroll
  for (int i = 0; i < 4; i++) { O[i] = (floatx4){0.f,0.f,0.f,0.f}; m_run[i] = -3.0e38f; l_run[i] = 0.f; }

  for (int kt = 0; kt <= qt; kt++) {
    __syncthreads();
#pragma unroll
    for (int pp = 0; pp < 4; pp++) {
      const int kb = pp * 4 + wave;
      bf16x4 pk;
#pragma unroll
      for (int c = 0; c < 4; c++)
        pk[c] = v[(((size_t)(b * L_ + kt * 64 + kb * 4 + c)) * NKV + g) * HD + lane];
      *(bf16x4*)&Vt[lane][kb * 4] = pk;
    }

    floatx4 S[4];
#pragma unroll
    for (int j = 0; j < 4; j++) {
      const __bf16* kp = k + (((size_t)(b * L_ + kt * 64 + j * 16 + fr)) * NKV + g) * HD;
      floatx4 sa = (floatx4){0.f,0.f,0.f,0.f};
#pragma unroll
      for (int s = 0; s < 2; s++) {
        bf16x8 kf = *(const bf16x8*)&kp[s * 32 + fq * 8];
        sa = __builtin_amdgcn_mfma_f32_16x16x32_bf16(qf[s], kf, sa, 0, 0, 0);
      }
      S[j] = sa;
    }

    if (kt == qt) {
      const int qbase = wave * 16 + fq * 4;
#pragma unroll
      for (int j = 0; j < 4; j++)
#pragma unroll
        for (int r = 0; r < 4; r++)
          if (j * 16 + fr > qbase + r) S[j][r] = -1.0e30f;
    }

    float rm[4], alpha[4], rsum[4];
#pragma unroll
    for (int r = 0; r < 4; r++)
      rm[r] = fmaxf(fmaxf(S[0][r], S[1][r]), fmaxf(S[2][r], S[3][r]));
#pragma unroll
    for (int msk = 1; msk <= 8; msk <<= 1)
#pragma unroll
      for (int r = 0; r < 4; r++) rm[r] = fmaxf(rm[r], __shfl_xor(rm[r], msk, 64));
#pragma unroll
    for (int r = 0; r < 4; r++) {
      float mnew = fmaxf(m_run[r], rm[r]);
      alpha[r] = __expf(m_run[r] - mnew);
      m_run[r] = mnew;
    }
#pragma unroll
    for (int j = 0; j < 4; j++)
#pragma unroll
      for (int r = 0; r < 4; r++) S[j][r] = __expf(S[j][r] - m_run[r]);
#pragma unroll
    for (int r = 0; r < 4; r++)
      rsum[r] = S[0][r] + S[1][r] + S[2][r] + S[3][r];
#pragma unroll
    for (int msk = 1; msk <= 8; msk <<= 1)
#pragma unroll
      for (int r = 0; r < 4; r++) rsum[r] += __shfl_xor(rsum[r], msk, 64);
#pragma unroll
    for (int r = 0; r < 4; r++) l_run[r] = l_run[r] * alpha[r] + rsum[r];
#pragma unroll
    for (int d4 = 0; d4 < 4; d4++)
#pragma unroll
      for (int r = 0; r < 4; r++) O[d4][r] *= alpha[r];

#pragma unroll
    for (int j = 0; j < 4; j++)
#pragma unroll
      for (int r = 0; r < 4; r++)
        Ps[wave][fq * 4 + r][j * 16 + fr] = (__bf16)S[j][r];

    __syncthreads();

#pragma unroll
    for (int s = 0; s < 2; s++) {
      bf16x8 pf = *(const bf16x8*)&Ps[wave][fr][s * 32 + fq * 8];
#pragma unroll
      for (int d4 = 0; d4 < 4; d4++) {
        bf16x8 vf = *(const bf16x8*)&Vt[d4 * 16 + fr][s * 32 + fq * 8];
        O[d4] = __builtin_amdgcn_mfma_f32_16x16x32_bf16(pf, vf, O[d4], 0, 0, 0);
      }
    }
  }

  float rl[4];
#pragma unroll
  for (int r = 0; r < 4; r++) rl[r] = 1.f / l_run[r];
#pragma unroll
  for (int d4 = 0; d4 < 4; d4++)
#pragma unroll
    for (int r = 0; r < 4; r++) {
      const int qg = l0 + wave * 16 + fq * 4 + r;
      out[((size_t)(b * L_ + qg)) * HID + h * 64 + d4 * 16 + fr] = (__bf16)(O[d4][r] * rl[r]);
    }
}

// ---------------- exact-fp32 recompute of the 32 dt columns of in_proj ------
__global__ __launch_bounds__(256) void dtfix_kernel(
    const float* __restrict__ hs_ln, const float* __restrict__ w, float* __restrict__ proj)
{
  const size_t t = blockIdx.x;
  const int tid = threadIdx.x;
  const int o = tid >> 3, part = tid & 7;
  const float* a = hs_ln + t * HID;
  const float* wr = w + (size_t)(INPROJ_N - MH + o) * HID;
  float s = 0.f;
  for (int kk = part * 4; kk < HID; kk += 32) {
    const float4 av = *(const float4*)&a[kk];
    const float4 wv = *(const float4*)&wr[kk];
    s += av.x * wv.x + av.y * wv.y + av.z * wv.z + av.w * wv.w;
  }
  s += __shfl_xor(s, 1);
  s += __shfl_xor(s, 2);
  s += __shfl_xor(s, 4);
  if (part == 0) proj[t * INPROJ_N + (INPROJ_N - MH) + o] = s * 1.32f; // SSM_IN*mup_dt
}

// ---------------- depthwise causal conv (MK=4) + bias + silu ----------------
__global__ __launch_bounds__(256) void conv_kernel(
    const float* __restrict__ proj, const float* __restrict__ cw,
    const float* __restrict__ cb, float* __restrict__ xbc)
{
  const int c = blockIdx.x * 256 + threadIdx.x;
  if (c >= CONV_DIM) return;
  const int t = blockIdx.y;
  const int l = t & (L_ - 1);
  float acc = cb[c];
#pragma unroll
  for (int kk = 0; kk < MK; kk++) {
    int lp = l - (MK - 1) + kk;
    if (lp >= 0)
      acc += proj[((size_t)(t - (MK - 1) + kk)) * INPROJ_N + DSSM + c] * cw[c * MK + kk];
  }
  xbc[(size_t)t * CONV_DIM + c] = acc / (1.f + __expf(-acc));
}

// ---------------- chunked Mamba2 scan, stage A: intra-chunk (MFMA) ----------
__global__ __launch_bounds__(256) void scanA_kernel(
    const float* __restrict__ xbc, const float* __restrict__ proj,
    const float* __restrict__ A_log, const float* __restrict__ dt_bias,
    const float* __restrict__ Dp,
    float* __restrict__ y, float* __restrict__ Tbuf,
    float* __restrict__ lam, float* __restrict__ dec)
{
  __shared__ __align__(16) __bf16 xT[64][72];    // [p][l]
  __shared__ __align__(16) __bf16 BTw[64][72];   // [s][l] (scaled)
  __shared__ __align__(16) __bf16 Braw[64][72];  // [l][s]
  __shared__ __align__(16) __bf16 Craw[64][72];  // [l][s]
  __shared__ __align__(16) __bf16 Ps[4][16][72]; // per-wave M strip
  __shared__ float dt_s[64], cum_s[64];

  const int tid = threadIdx.x;
  const int lane = tid & 63, wave = tid >> 6;
  const int fr = lane & 15, fq = lane >> 4;
  const int c = blockIdx.x, h = blockIdx.y, b = blockIdx.z;
  const int t0 = b * L_ + c * CL;
  const float Ah = -expf(A_log[h]);
  const float dtb = dt_bias[h], Dh = Dp[h];

  if (wave == 0) {
    float draw = proj[(size_t)(t0 + lane) * INPROJ_N + (INPROJ_N - MH) + h];
    float dtv = draw + dtb;
    dtv = (dtv > 20.f) ? dtv : log1pf(__expf(dtv));
    float cs = dtv * Ah;
#pragma unroll
    for (int d = 1; d < 64; d <<= 1) {
      float nv = __shfl_up(cs, d, 64);
      if (lane >= d) cs += nv;
    }
    dt_s[lane] = dtv;
    cum_s[lane] = cs;
  }

#pragma unroll
  for (int pass = 0; pass < 4; pass++) {
    const int l = pass * 16 + (tid >> 4);
    const int s4 = (tid & 15) * 4;
    const float* rowp = xbc + (size_t)(t0 + l) * CONV_DIM;
    float4 xv = *(const float4*)&rowp[h * 64 + s4];
    float4 bv = *(const float4*)&rowp[DSSM + s4];
    float4 cv = *(const float4*)&rowp[DSSM + MS + s4];
    xT[s4 + 0][l] = (__bf16)xv.x;
    xT[s4 + 1][l] = (__bf16)xv.y;
    xT[s4 + 2][l] = (__bf16)xv.z;
    xT[s4 + 3][l] = (__bf16)xv.w;
    bf16x4 b4; b4[0]=(__bf16)bv.x; b4[1]=(__bf16)bv.y; b4[2]=(__bf16)bv.z; b4[3]=(__bf16)bv.w;
    *(bf16x4*)&Braw[l][s4] = b4;
    bf16x4 c4; c4[0]=(__bf16)cv.x; c4[1]=(__bf16)cv.y; c4[2]=(__bf16)cv.z; c4[3]=(__bf16)cv.w;
    *(bf16x4*)&Craw[l][s4] = c4;
  }
  __syncthreads();

  const float cend = cum_s[63];
#pragma unroll
  for (int pass = 0; pass < 4; pass++) {
    const int l = pass * 16 + (tid >> 4);
    const int s4 = (tid & 15) * 4;
    const float wl = __expf(cend - cum_s[l]) * dt_s[l];
    float4 bv = *(const float4*)&xbc[(size_t)(t0 + l) * CONV_DIM + DSSM + s4];
    BTw[s4 + 0][l] = (__bf16)(bv.x * wl);
    BTw[s4 + 1][l] = (__bf16)(bv.y * wl);
    BTw[s4 + 2][l] = (__bf16)(bv.z * wl);
    BTw[s4 + 3][l] = (__bf16)(bv.w * wl);
  }

  {
    bf16x8 aF0 = *(const bf16x8*)&Craw[wave * 16 + fr][fq * 8];
    bf16x8 aF1 = *(const bf16x8*)&Craw[wave * 16 + fr][fq * 8 + 32];
#pragma unroll
    for (int j = 0; j < 4; j++) {
      floatx4 s = (floatx4){0.f,0.f,0.f,0.f};
      bf16x8 b0 = *(const bf16x8*)&Braw[j * 16 + fr][fq * 8];
      bf16x8 b1 = *(const bf16x8*)&Braw[j * 16 + fr][fq * 8 + 32];
      s = __builtin_amdgcn_mfma_f32_16x16x32_bf16(aF0, b0, s, 0, 0, 0);
      s = __builtin_amdgcn_mfma_f32_16x16x32_bf16(aF1, b1, s, 0, 0, 0);
      const int m = j * 16 + fr;
      const float dtm = dt_s[m], cmm = cum_s[m];
#pragma unroll
      for (int r = 0; r < 4; r++) {
        const int lR = wave * 16 + fq * 4 + r;
        float f = (m <= lR) ? __expf(cum_s[lR] - cmm) * dtm : 0.f;
        Ps[wave][fq * 4 + r][m] = (__bf16)(s[r] * f);
      }
    }
  }
  __syncthreads();

  {
    bf16x8 aF0 = *(const bf16x8*)&Ps[wave][fr][fq * 8];
    bf16x8 aF1 = *(const bf16x8*)&Ps[wave][fr][fq * 8 + 32];
#pragma unroll
    for (int j = 0; j < 4; j++) {
      floatx4 s = (floatx4){0.f,0.f,0.f,0.f};
      bf16x8 b0 = *(const bf16x8*)&xT[j * 16 + fr][fq * 8];
      bf16x8 b1 = *(const bf16x8*)&xT[j * 16 + fr][fq * 8 + 32];
      s = __builtin_amdgcn_mfma_f32_16x16x32_bf16(aF0, b0, s, 0, 0, 0);
      s = __builtin_amdgcn_mfma_f32_16x16x32_bf16(aF1, b1, s, 0, 0, 0);
      const int p = j * 16 + fr;
#pragma unroll
      for (int r = 0; r < 4; r++) {
        const int lR = wave * 16 + fq * 4 + r;
        float xval = (float)xT[p][lR];
        y[(size_t)(t0 + lR) * DSSM + h * 64 + p] = s[r] + Dh * xval;
      }
    }
  }

  {
    float* Tb = Tbuf + ((size_t)((b * MH + h) * CH + c)) * 4096;
    bf16x8 aF0 = *(const bf16x8*)&xT[wave * 16 + fr][fq * 8];
    bf16x8 aF1 = *(const bf16x8*)&xT[wave * 16 + fr][fq * 8 + 32];
#pragma unroll
    for (int j = 0; j < 4; j++) {
      floatx4 s = (floatx4){0.f,0.f,0.f,0.f};
      bf16x8 b0 = *(const bf16x8*)&BTw[j * 16 + fr][fq * 8];
      bf16x8 b1 = *(const bf16x8*)&BTw[j * 16 + fr][fq * 8 + 32];
      s = __builtin_amdgcn_mfma_f32_16x16x32_bf16(aF0, b0, s, 0, 0, 0);
      s = __builtin_amdgcn_mfma_f32_16x16x32_bf16(aF1, b1, s, 0, 0, 0);
#pragma unroll
      for (int r = 0; r < 4; r++)
        Tb[(wave * 16 + fq * 4 + r) * 64 + j * 16 + fr] = s[r];
    }
  }

  if (tid == 0) lam[(b * MH + h) * CH + c] = __expf(cend);
  if (tid >= 64 && tid < 128)
    dec[((size_t)((b * MH + h) * CH + c)) * 64 + (tid - 64)] = __expf(cum_s[tid - 64]);
}

// ---------------- chunked scan, stage B: inter-chunk state scan -------------
__global__ __launch_bounds__(256) void scanB_kernel(
    const float* __restrict__ xbc, const float* __restrict__ Tbuf,
    const float* __restrict__ lam, const float* __restrict__ dec,
    float* __restrict__ y)
{
  __shared__ __align__(16) float S[64][68];
  __shared__ __align__(16) __bf16 Cc[64][72];
  __shared__ float decl[64];
  const int tid = threadIdx.x;
  const int lane = tid & 63, wave = tid >> 6;
  const int fr = lane & 15, fq = lane >> 4;
  const int h = blockIdx.x, b = blockIdx.y;

  const int sown = tid & 63, pbase = (tid >> 6) * 16;
#pragma unroll
  for (int i = 0; i < 16; i++) S[pbase + i][sown] = 0.f;
  __syncthreads();

  for (int c = 0; c < CH; c++) {
    const int t0 = b * L_ + c * CL;
#pragma unroll
    for (int pass = 0; pass < 4; pass++) {
      const int l = pass * 16 + (tid >> 4);
      const int s4 = (tid & 15) * 4;
      float4 cv = *(const float4*)&xbc[(size_t)(t0 + l) * CONV_DIM + DSSM + MS + s4];
      bf16x4 c4; c4[0]=(__bf16)cv.x; c4[1]=(__bf16)cv.y; c4[2]=(__bf16)cv.z; c4[3]=(__bf16)cv.w;
      *(bf16x4*)&Cc[l][s4] = c4;
    }
    if (tid < 64) decl[tid] = dec[((size_t)((b * MH + h) * CH + c)) * 64 + tid];
    __syncthreads();

    if (c > 0) {
      bf16x8 aF0 = *(const bf16x8*)&Cc[wave * 16 + fr][fq * 8];
      bf16x8 aF1 = *(const bf16x8*)&Cc[wave * 16 + fr][fq * 8 + 32];
#pragma unroll
      for (int j = 0; j < 4; j++) {
        const float* srow = &S[j * 16 + fr][0];
        float4 s0 = *(const float4*)&srow[fq * 8];
        float4 s1 = *(const float4*)&srow[fq * 8 + 4];
        float4 s2 = *(const float4*)&srow[fq * 8 + 32];
        float4 s3 = *(const float4*)&srow[fq * 8 + 36];
        bf16x8 b0 = pack8(s0, s1, 1.f);
        bf16x8 b1 = pack8(s2, s3, 1.f);
        floatx4 acc = (floatx4){0.f,0.f,0.f,0.f};
        acc = __builtin_amdgcn_mfma_f32_16x16x32_bf16(aF0, b0, acc, 0, 0, 0);
        acc = __builtin_amdgcn_mfma_f32_16x16x32_bf16(aF1, b1, acc, 0, 0, 0);
        const int p = j * 16 + fr;
#pragma unroll
        for (int r = 0; r < 4; r++) {
          const int lR = wave * 16 + fq * 4 + r;
          float* yp = &y[(size_t)(t0 + lR) * DSSM + h * 64 + p];
          *yp += decl[lR] * acc[r];
        }
      }
    }
    __syncthreads();

    const float lc = lam[(b * MH + h) * CH + c];
    const float* Tb = Tbuf + ((size_t)((b * MH + h) * CH + c)) * 4096;
#pragma unroll
    for (int i = 0; i < 16; i++) {
      float tv = Tb[(pbase + i) * 64 + sown];
      S[pbase + i][sown] = lc * S[pbase + i][sown] + tv;
    }
    __syncthreads();
  }
}

// ---------------- gating (y * silu(z)) + RMSNorm -> bf16 ----------------
__global__ __launch_bounds__(256) void gating_kernel(
    const float* __restrict__ y, const float* __restrict__ proj,
    const float* __restrict__ nw, __bf16* __restrict__ g)
{
  __shared__ float buf[DSSM];
  __shared__ float red[8];
  const int tid = threadIdx.x;
  const size_t t = blockIdx.x;
  float ss = 0.f;
  for (int i = tid; i < DSSM; i += 256) {
    float zv = proj[t * INPROJ_N + i];
    float yv = y[t * DSSM + i];
    float gv = yv * zv / (1.f + __expf(-zv));
    buf[i] = gv;
    ss += gv * gv;
  }
  float tot = block_sum(ss, red);
  float inv = rsqrtf(tot / (float)DSSM + 1e-5f);
  for (int i = tid; i < DSSM; i += 256) g[t * DSSM + i] = (__bf16)(buf[i] * inv * nw[i]);
}

// ---------------- SwiGLU activation -> bf16 (x4 vectorized) ----------------
__global__ __launch_bounds__(256) void act_kernel(
    const float* __restrict__ gu, __bf16* __restrict__ act)
{
  const int i = (blockIdx.x * 256 + threadIdx.x) * 4;
  const size_t t = blockIdx.y;
  float4 g4 = *(const float4*)&gu[t * (2 * INTER) + i];
  float4 u4 = *(const float4*)&gu[t * (2 * INTER) + INTER + i];
  bf16x4 o;
  float gt;
  gt = g4.x * 0.9f; o[0] = (__bf16)(gt / (1.f + __expf(-gt)) * u4.x);
  gt = g4.y * 0.9f; o[1] = (__bf16)(gt / (1.f + __expf(-gt)) * u4.y);
  gt = g4.z * 0.9f; o[2] = (__bf16)(gt / (1.f + __expf(-gt)) * u4.z);
  gt = g4.w * 0.9f; o[3] = (__bf16)(gt / (1.f + __expf(-gt)) * u4.w);
  *(bf16x4*)&act[t * INTER + i] = o;
}

// ---------------- launcher ----------------
extern "C" void kernel_launch(void* const* d_in, const int* in_sizes, int n_in,
                              void* d_out, int out_size, void* d_ws, size_t ws_size,
                              hipStream_t stream)
{
  const float* hidden      = (const float*)d_in[0];
  const int*   positions   = (const int*)d_in[1];
  const float* w_in_ln     = (const float*)d_in[2];
  const float* qkv_w       = (const float*)d_in[3];
  const float* o_w         = (const float*)d_in[4];
  const float* in_proj_w   = (const float*)d_in[5];
  const float* conv_w      = (const float*)d_in[6];
  const float* conv_b      = (const float*)d_in[7];
  const float* A_log       = (const float*)d_in[8];
  const float* dt_bias     = (const float*)d_in[9];
  const float* Dp          = (const float*)d_in[10];
  const float* ssm_norm_w  = (const float*)d_in[11];
  const float* out_proj_w  = (const float*)d_in[12];
  const float* w_pre_ff_ln = (const float*)d_in[13];
  const float* gate_up_w   = (const float*)d_in[14];
  const float* down_w      = (const float*)d_in[15];
  (void)in_sizes; (void)n_in; (void)out_size; (void)ws_size;

  float* ws   = (float*)d_ws;
  float* outp = (float*)d_out;

  float*  h2    = ws + OFF_H2;
  float*  mup   = ws + OFF_MUP;
  __bf16* wqkv  = (__bf16*)(ws + OFF_WQKV);
  __bf16* win   = (__bf16*)(ws + OFF_WIN);
  __bf16* wo    = (__bf16*)(ws + OFF_WO);
  __bf16* wop   = (__bf16*)(ws + OFF_WOP);
  __bf16* hsb   = (__bf16*)(ws + OFF_HSB);
  float*  hsf   = ws + OFF_HSF;
  float*  qkv   = ws + OFF_QKV;
  __bf16* qb    = (__bf16*)(ws + OFF_Q);
  __bf16* kb    = (__bf16*)(ws + OFF_K);
  __bf16* vb    = (__bf16*)(ws + OFF_V);
  __bf16* attb  = (__bf16*)(ws + OFF_ATT);
  float*  proj  = ws + OFF_PROJ;
  float*  xbc   = ws + OFF_XBC;
  float*  y     = ws + OFF_Y;
  __bf16* gb    = (__bf16*)(ws + OFF_G);
  float*  Tbuf  = ws + OFF_TB;
  float*  dec   = ws + OFF_DEC;
  float*  lam   = ws + OFF_LAM;
  __bf16* hs2b  = (__bf16*)(ws + OFF_HS2B);
  float*  gu    = ws + OFF_GU;
  __bf16* actb  = (__bf16*)(ws + OFF_ACTB);
  __bf16* wb2   = (__bf16*)(ws + OFF_WB2);

  // phase-1 weight conversions (fp32 -> bf16)
  cvt_kernel<<<2048, 256, 0, stream>>>(qkv_w, wqkv, 786432);
  cvt_kernel<<<2048, 256, 0, stream>>>(in_proj_w, win, 1089536);
  cvt_kernel<<<2048, 256, 0, stream>>>(o_w, wo, 524288);
  cvt_kernel<<<2048, 256, 0, stream>>>(out_proj_w, wop, 524288);
  mup_kernel<<<17, 256, 0, stream>>>(mup);
  rms_kernel<<<T_, 256, 0, stream>>>(hidden, w_in_ln, hsb, hsf, h2);

  // attention branch
  gemm_bf_kernel<<<dim3(16, 24, 1), 256, 0, stream>>>(hsb, wqkv, qkv, nullptr,
                                                      QKV_N, HID, QKV_N, 1.2f);
  rope_kernel<<<T_, 256, 0, stream>>>(qkv, positions, qb, kb, vb);
  fattn_kernel<<<dim3(L_ / 64, NH, B_), 256, 0, stream>>>(qb, kb, vb, attb);
  gemm256p_kernel<<<dim3(8, 8, 4), 512, 0, stream>>>(attb, wo, h2,
                                                     HID, HID, HID, 0.8f);  // atomic += into residual

  // mamba branch
  gemm_bf_kernel<<<dim3(16, 34, 1), 256, 0, stream>>>(hsb, win, proj, mup,
                                                      INPROJ_N, HID, INPROJ_N, 1.1f);
  dtfix_kernel<<<T_, 256, 0, stream>>>(hsf, in_proj_w, proj);
  conv_kernel<<<dim3(9, T_), 256, 0, stream>>>(proj, conv_w, conv_b, xbc);
  scanA_kernel<<<dim3(CH, MH, B_), 256, 0, stream>>>(xbc, proj, A_log, dt_bias, Dp,
                                                     y, Tbuf, lam, dec);
  scanB_kernel<<<dim3(MH, B_), 256, 0, stream>>>(xbc, Tbuf, lam, dec, y);
  gating_kernel<<<T_, 256, 0, stream>>>(y, proj, ssm_norm_w, gb);
  gemm256p_kernel<<<dim3(8, 8, 4), 512, 0, stream>>>(gb, wop, h2,
                                                     HID, HID, HID, 0.9f);  // atomic += into residual

  // MLP (wb2 time-shared: gate half -> up half -> down_w)
  rms_kernel<<<T_, 256, 0, stream>>>(h2, w_pre_ff_ln, hs2b, nullptr, nullptr);
  cvt_kernel<<<2048, 256, 0, stream>>>(gate_up_w, wb2, 2097152);
  gemm256p_kernel<<<dim3(8, 32, 1), 512, 0, stream>>>(hs2b, wb2, gu,
                                                      INTER, HID, 2 * INTER, 1.0f);
  cvt_kernel<<<2048, 256, 0, stream>>>(gate_up_w + (size_t)INTER * HID, wb2, 2097152);
  gemm256p_kernel<<<dim3(8, 32, 1), 512, 0, stream>>>(hs2b, wb2, gu + INTER,
                                                      INTER, HID, 2 * INTER, 1.0f);
  act_kernel<<<dim3(INTER / 1024, T_), 256, 0, stream>>>(gu, actb);
  cvt_kernel<<<2048, 256, 0, stream>>>(down_w, wb2, 2097152);
  copy_kernel<<<4096, 256, 0, stream>>>(h2, outp);
  gemm256p_kernel<<<dim3(8, 8, 4), 512, 0, stream>>>(actb, wb2, outp,
                                                     HID, INTER, HID, 0.8f); // atomic += onto residual copy
}